// Round 19
// baseline (310.546 us; speedup 1.0000x reference)
//
#include <hip/hip_runtime.h>
#include <hip/hip_bf16.h>

// Problem constants
#define BDIM 4
#define KDIM 1024
#define EDIM 16384
#define NSEQ (BDIM * KDIM)   // 4096
#define REG  25856           // per-sequence LDS region stride (bytes)
#define MOFF 9216            // s_m offset within region (after s_vt [128][36])

typedef unsigned short ushort_t;
typedef unsigned int   uint32;

typedef __bf16 bf16x8 __attribute__((ext_vector_type(8)));
typedef float  f32x4  __attribute__((ext_vector_type(4)));

#define MFMA(A, B, C) __builtin_amdgcn_mfma_f32_16x16x32_bf16((A), (B), (C), 0, 0, 0)
#define PRIO_HI() __builtin_amdgcn_s_setprio(1)
#define PRIO_LO() __builtin_amdgcn_s_setprio(0)

__device__ __forceinline__ float bf2f(uint32 u) {
    union { uint32 i; float f; } v; v.i = u << 16; return v.f;
}
__device__ __forceinline__ ushort_t f2bf(float f) {
    union { float f; uint32 i; } v; v.f = f;
    uint32 r = (v.i + 0x7fffu + ((v.i >> 16) & 1u)) >> 16;
    return (ushort_t)r;
}
// hardware packed cvt: {lo=bf16(a), hi=bf16(b)}, RNE
__device__ __forceinline__ uint32 cvtpk(float a, float b) {
    uint32 r;
    asm("v_cvt_pk_bf16_f32 %0, %1, %2" : "=v"(r) : "v"(a), "v"(b));
    return r;
}
__device__ __forceinline__ ushort_t f2bf_hw(float f) { return (ushort_t)cvtpk(f, f); }

__device__ __forceinline__ void unpack8(uint4 v, float* dst) {
    const uint32* pv = (const uint32*)&v;
#pragma unroll
    for (int q = 0; q < 4; q++) {
        uint32 w = pv[q];
        dst[2 * q]     = bf2f(w & 0xffffu);
        dst[2 * q + 1] = bf2f(w >> 16);
    }
}
// pack 16 floats -> 16 bf16 (32B) at p (16B-aligned)
__device__ __forceinline__ void store16bf(ushort_t* p, const float* v) {
    uint32 w[8];
#pragma unroll
    for (int q = 0; q < 8; q++) w[q] = cvtpk(v[2 * q], v[2 * q + 1]);
    ((uint4*)p)[0] = make_uint4(w[0], w[1], w[2], w[3]);
    ((uint4*)p)[1] = make_uint4(w[4], w[5], w[6], w[7]);
}

// ---------------------------------------------------------------------------
// Weight pre-conversion fp32 -> bf16 into ws:
//   wqkv [384][128] @0 | wout [128][128] @49152 | w1 [512][128] @65536
//   w2 [128][512] @131072 | gcnw [128][128] @196608   (elements)
// ---------------------------------------------------------------------------
#define NWCVT 212992
__global__ void k_prep(const float* __restrict__ wq, const float* __restrict__ wo,
                       const float* __restrict__ w1, const float* __restrict__ w2,
                       const float* __restrict__ wg, ushort_t* __restrict__ dst) {
    int i = blockIdx.x * 256 + threadIdx.x;
    if (i >= NWCVT) return;
    float v;
    if      (i <  49152) v = wq[i];
    else if (i <  65536) v = wo[i - 49152];
    else if (i < 131072) v = w1[i - 65536];
    else if (i < 196608) v = w2[i - 131072];
    else                 v = wg[i - 196608];
    dst[i] = f2bf(v);
}

// ---------------------------------------------------------------------------
// Fused GCN graph preprocessing: one block per batch b (1024 threads).
// LDS histogram (deg,count) -> LDS Hillis-Steele scan -> LDS-cursor fill.
// Writes deg/count/offs (global, for k_gather) and elist.
// ---------------------------------------------------------------------------
__global__ __launch_bounds__(1024)
void k_graph(const int* __restrict__ ei, const float* __restrict__ ew,
             float* __restrict__ deg, int* __restrict__ count,
             int* __restrict__ offs, int* __restrict__ elist)
{
    const int b = blockIdx.x, i = threadIdx.x;
    __shared__ float degL[KDIM];
    __shared__ int   cntL[KDIM];
    __shared__ int   curL[KDIM];
    __shared__ int   sc[KDIM];
    const int* colb = ei + (size_t)b * 2 * EDIM + EDIM;
    const float* ewb = ew + (size_t)b * EDIM;

    degL[i] = 1.0f;           // self-loop weight
    cntL[i] = 0;
    __syncthreads();
    // histogram (LDS atomics)
#pragma unroll
    for (int it = 0; it < EDIM / KDIM; it++) {
        const int e = it * KDIM + i;
        const int col = colb[e];
        atomicAdd(&degL[col], ewb[e]);
        atomicAdd(&cntL[col], 1);
    }
    __syncthreads();
    const int c = cntL[i];
    sc[i] = c;
    __syncthreads();
    // Hillis-Steele inclusive scan
#pragma unroll 1
    for (int off = 1; off < KDIM; off <<= 1) {
        int t = (i >= off) ? sc[i - off] : 0;
        __syncthreads();
        sc[i] += t;
        __syncthreads();
    }
    const int excl = sc[i] - c;
    curL[i] = excl;
    deg[b * KDIM + i]   = degL[i];
    count[b * KDIM + i] = c;
    offs[b * KDIM + i]  = excl;
    __syncthreads();
    // bucket fill (LDS cursor)
#pragma unroll
    for (int it = 0; it < EDIM / KDIM; it++) {
        const int e = it * KDIM + i;
        const int col = colb[e];
        const int pos = atomicAdd(&curL[col], 1);
        elist[(size_t)b * EDIM + pos] = e;
    }
}

// ---------------------------------------------------------------------------
// Fused transformer layer (r17/r18, session optimum): 2 seq/block,
// shared-weight QKV/W_out/FFN2/GCN, barrier-free striped attention,
// 12 barriers/block, T5 s_setprio around MFMA clusters (VGPR 84 -> 3 blk/CU).
// NO launch_bounds min-waves (pinned miscompile r7/r8).
// LDS 2 x 25856 = 51712 B.
// Region: s_h[32][136]<alias>s_vt[128][36] @0; s_m[32][260]|s_mf[32][130] @9216.
// ---------------------------------------------------------------------------
__global__ __launch_bounds__(256)
void k_transformer(const float* __restrict__ x,
                   const ushort_t* __restrict__ wq_bf, const float* __restrict__ b_qkv,
                   const ushort_t* __restrict__ wo_bf, const float* __restrict__ b_out,
                   const ushort_t* __restrict__ w1_bf, const float* __restrict__ b1,
                   const ushort_t* __restrict__ w2_bf, const float* __restrict__ b2,
                   const ushort_t* __restrict__ wg_bf,
                   const float* __restrict__ ln1g, const float* __restrict__ ln1b,
                   const float* __restrict__ ln2g, const float* __restrict__ ln2b,
                   float* __restrict__ out_xt, ushort_t* __restrict__ hh)
{
    const int n0   = blockIdx.x * 2;
    const int tid  = threadIdx.x;
    const int wave = tid >> 6;
    const int lane = tid & 63;
    const int lh   = lane & 15;      // M-row / N-col within 16x16 tile
    const int lg   = lane >> 4;      // k-group (8 elems each)
    const int l    = tid >> 3;       // per-thread row (LN phases)
    const int ds   = (tid & 7) * 16;

    __shared__ __align__(16) char smem[2 * REG];
#define SH(s)  ((ushort_t*)(smem + (s) * REG))
#define SVT(s) ((ushort_t*)(smem + (s) * REG))
#define SM(s)  ((ushort_t*)(smem + (s) * REG + MOFF))
#define SMF(s) ((float*)(smem + (s) * REG + MOFF))

    // ---- load h0 for both sequences -> s_h(s) (bf16) ----
#pragma unroll
    for (int s = 0; s < 2; s++) {
        const float4* px = (const float4*)(x + (size_t)(n0 + s) * 4096 + tid * 16);
        float h0[16];
#pragma unroll
        for (int q = 0; q < 4; q++) {
            float4 v = px[q];
            h0[4 * q] = v.x; h0[4 * q + 1] = v.y; h0[4 * q + 2] = v.z; h0[4 * q + 3] = v.w;
        }
        store16bf(SH(s) + l * 136 + ds, h0);
    }
    __syncthreads();                                   // B1

    // ================= QKV (shared weights, 2 chains per load) ===============
    {
        bf16x8 af[2][2][4];   // [s][mt][kk]
#pragma unroll
        for (int s = 0; s < 2; s++)
#pragma unroll
            for (int mt = 0; mt < 2; mt++)
#pragma unroll
                for (int kk = 0; kk < 4; kk++)
                    af[s][mt][kk] = *(const bf16x8*)(SH(s) + (mt * 16 + lh) * 136 + kk * 32 + lg * 8);
        __syncthreads();                               // B2: s_h dead; V^T may write region0

        const int ntb = wave * 6;
        float biasv[6];
#pragma unroll
        for (int j = 0; j < 6; j++) biasv[j] = b_qkv[(ntb + j) * 16 + lh];
#pragma unroll
        for (int j = 0; j < 6; j++) {
            bf16x8 bw[4];
#pragma unroll
            for (int kk = 0; kk < 4; kk++)
                bw[kk] = *(const bf16x8*)(wq_bf + (size_t)((ntb + j) * 16 + lh) * 128 + kk * 32 + lg * 8);
            f32x4 A[2][2];
#pragma unroll
            for (int s = 0; s < 2; s++) { A[s][0] = f32x4{0.f,0.f,0.f,0.f}; A[s][1] = f32x4{0.f,0.f,0.f,0.f}; }
            PRIO_HI();
#pragma unroll
            for (int kk = 0; kk < 4; kk++) {
#pragma unroll
                for (int s = 0; s < 2; s++) {
                    A[s][0] = MFMA(af[s][0][kk], bw[kk], A[s][0]);
                    A[s][1] = MFMA(af[s][1][kk], bw[kk], A[s][1]);
                }
            }
            PRIO_LO();
            const int nt  = ntb + j;
            const int col = nt * 16 + lh;
            const float bias = biasv[j];
#pragma unroll
            for (int s = 0; s < 2; s++) {
                if (nt < 16) {          // Q (cols 0-127) | K (cols 128-255)
                    const int r0 = lg * 4;
#pragma unroll
                    for (int i = 0; i < 4; i++) {
                        SM(s)[(r0 + i) * 260 + col]      = f2bf_hw(A[s][0][i] + bias);
                        SM(s)[(16 + r0 + i) * 260 + col] = f2bf_hw(A[s][1][i] + bias);
                    }
                } else {                // V -> transposed s_vt[dh][key] (region0)
                    const int vc = col - 256;
                    uint32 p01 = cvtpk(A[s][0][0] + bias, A[s][0][1] + bias);
                    uint32 p23 = cvtpk(A[s][0][2] + bias, A[s][0][3] + bias);
                    uint32 q01 = cvtpk(A[s][1][0] + bias, A[s][1][1] + bias);
                    uint32 q23 = cvtpk(A[s][1][2] + bias, A[s][1][3] + bias);
                    *(uint32*)&SVT(s)[vc * 36 + lg * 4]          = p01;
                    *(uint32*)&SVT(s)[vc * 36 + lg * 4 + 2]      = p23;
                    *(uint32*)&SVT(s)[vc * 36 + 16 + lg * 4]     = q01;
                    *(uint32*)&SVT(s)[vc * 36 + 16 + lg * 4 + 2] = q23;
                }
            }
        }
    }
    __syncthreads();                                   // B3: Q,K,V^T visible (both s)

    // ============ attention: BARRIER-FREE per-wave striped section ===========
    {
        // W_out weights + biases loaded ONCE, early (consumed after B6)
        bf16x8 wbo[2][4];
#pragma unroll
        for (int j = 0; j < 2; j++)
#pragma unroll
            for (int kk = 0; kk < 4; kk++)
                wbo[j][kk] = *(const bf16x8*)(wo_bf + (size_t)((wave * 2 + j) * 16 + lh) * 128 + kk * 32 + lg * 8);
        float bo0 = b_out[(wave * 2 + 0) * 16 + lh];
        float bo1 = b_out[(wave * 2 + 1) * 16 + lh];

#pragma unroll
        for (int s = 0; s < 2; s++) {
            // ---- QK^T both heads (must precede P: P(hd0) overwrites Q(hd1)) --
            f32x4 sA[2][2][2];   // [hd][mt][nt]
            bf16x8 bz = {};
            PRIO_HI();
#pragma unroll
            for (int hd = 0; hd < 2; hd++) {
                const int h8 = wave * 2 + hd;
#pragma unroll
                for (int mt = 0; mt < 2; mt++) {
                    bf16x8 aq = *(const bf16x8*)(SM(s) + (mt * 16 + lh) * 260 + h8 * 16 + (lg & 1) * 8);
#pragma unroll
                    for (int nt = 0; nt < 2; nt++) {
                        bf16x8 bk = bz;
                        if (lg < 2)
                            bk = *(const bf16x8*)(SM(s) + (nt * 16 + lh) * 260 + 128 + h8 * 16 + lg * 8);
                        f32x4 z = {0.f,0.f,0.f,0.f};
                        sA[hd][mt][nt] = MFMA(aq, bk, z);
                    }
                }
            }
            PRIO_LO();
            // ---- softmax + P into own stripes (wave-local) ----
#pragma unroll
            for (int hd = 0; hd < 2; hd++) {
                const int cb = hd ? (128 + wave * 32) : (wave * 32);
#pragma unroll
                for (int mt = 0; mt < 2; mt++) {
#pragma unroll
                    for (int i = 0; i < 4; i++) {
                        float e0 = __expf(sA[hd][mt][0][i] * 0.25f);
                        float e1 = __expf(sA[hd][mt][1][i] * 0.25f);
                        float sm = e0 + e1;
                        sm += __shfl_xor(sm, 1); sm += __shfl_xor(sm, 2);
                        sm += __shfl_xor(sm, 4); sm += __shfl_xor(sm, 8);
                        float inv = 1.0f / sm;
                        const int row = mt * 16 + lg * 4 + i;
                        SM(s)[row * 260 + cb + lh]      = f2bf_hw(e0 * inv);
                        SM(s)[row * 260 + cb + 16 + lh] = f2bf_hw(e1 * inv);
                    }
                }
            }
            // ---- PV -> O into own col stripe (wave-local) ----
            PRIO_HI();
#pragma unroll
            for (int hd = 0; hd < 2; hd++) {
                const int h8 = wave * 2 + hd;
                const int cb = hd ? (128 + wave * 32) : (wave * 32);
                bf16x8 bv = *(const bf16x8*)(SVT(s) + (h8 * 16 + lh) * 36 + lg * 8);
#pragma unroll
                for (int mt = 0; mt < 2; mt++) {
                    bf16x8 ap = *(const bf16x8*)(SM(s) + (mt * 16 + lh) * 260 + cb + lg * 8);
                    f32x4 z = {0.f,0.f,0.f,0.f};
                    f32x4 o = MFMA(ap, bv, z);
                    const int r0 = mt * 16 + lg * 4, c = h8 * 16 + lh;
#pragma unroll
                    for (int i = 0; i < 4; i++)
                        SM(s)[(r0 + i) * 260 + c] = f2bf_hw(o[i]);
                }
            }
            PRIO_LO();
        }
        __syncthreads();                               // B6: O complete (both s)
        // W_out -> u (bf16, region0(s)); shared wbo, 2 chains
#pragma unroll
        for (int s = 0; s < 2; s++) {
            bf16x8 af2[2][4];
#pragma unroll
            for (int mt = 0; mt < 2; mt++)
#pragma unroll
                for (int kk = 0; kk < 4; kk++)
                    af2[mt][kk] = *(const bf16x8*)(SM(s) + (mt * 16 + lh) * 260 + kk * 32 + lg * 8);
#pragma unroll
            for (int j = 0; j < 2; j++) {
                f32x4 a0 = {0.f,0.f,0.f,0.f}, a1 = {0.f,0.f,0.f,0.f};
                PRIO_HI();
#pragma unroll
                for (int kk = 0; kk < 4; kk++) {
                    a0 = MFMA(af2[0][kk], wbo[j][kk], a0);
                    a1 = MFMA(af2[1][kk], wbo[j][kk], a1);
                }
                PRIO_LO();
                const int col = (wave * 2 + j) * 16 + lh;
                const float bias = j ? bo1 : bo0;
#pragma unroll
                for (int i = 0; i < 4; i++) {
                    SH(s)[(lg * 4 + i) * 136 + col]      = f2bf_hw(a0[i] + bias);
                    SH(s)[(16 + lg * 4 + i) * 136 + col] = f2bf_hw(a1[i] + bias);
                }
            }
        }
        __syncthreads();                               // B7: u visible (both s)
        // LN1: h1 = LN(h0 + u) -> s_h(s), both s (gamma/beta loaded once)
        {
            float g[16], be[16];
            {
                const float4* pg = (const float4*)(ln1g + ds);
                const float4* pb = (const float4*)(ln1b + ds);
#pragma unroll
                for (int q = 0; q < 4; q++) {
                    float4 vg = pg[q], vb = pb[q];
                    g[4*q]=vg.x; g[4*q+1]=vg.y; g[4*q+2]=vg.z; g[4*q+3]=vg.w;
                    be[4*q]=vb.x; be[4*q+1]=vb.y; be[4*q+2]=vb.z; be[4*q+3]=vb.w;
                }
            }
#pragma unroll
            for (int s = 0; s < 2; s++) {
                const float4* px = (const float4*)(x + (size_t)(n0 + s) * 4096 + tid * 16);
                float4 hx0 = px[0], hx1 = px[1], hx2 = px[2], hx3 = px[3];
                float h0v[16];
                { float4 v = hx0; h0v[0]=v.x; h0v[1]=v.y; h0v[2]=v.z; h0v[3]=v.w; }
                { float4 v = hx1; h0v[4]=v.x; h0v[5]=v.y; h0v[6]=v.z; h0v[7]=v.w; }
                { float4 v = hx2; h0v[8]=v.x; h0v[9]=v.y; h0v[10]=v.z; h0v[11]=v.w; }
                { float4 v = hx3; h0v[12]=v.x; h0v[13]=v.y; h0v[14]=v.z; h0v[15]=v.w; }
                float t[16]; float sum = 0.f;
#pragma unroll
                for (int i = 0; i < 16; i++) {
                    t[i] = h0v[i] + bf2f((uint32)SH(s)[l * 136 + ds + i]);
                    sum += t[i];
                }
                sum += __shfl_xor(sum, 1); sum += __shfl_xor(sum, 2); sum += __shfl_xor(sum, 4);
                float mean = sum * (1.f / 128.f);
                float vs = 0.f;
#pragma unroll
                for (int i = 0; i < 16; i++) { float d = t[i] - mean; vs += d * d; }
                vs += __shfl_xor(vs, 1); vs += __shfl_xor(vs, 2); vs += __shfl_xor(vs, 4);
                float rs = rsqrtf(vs * (1.f / 128.f) + 1e-5f);
                float h1v[16];
#pragma unroll
                for (int i = 0; i < 16; i++)
                    h1v[i] = (t[i] - mean) * rs * g[i] + be[i];
                store16bf(SH(s) + l * 136 + ds, h1v);  // own addrs
            }
        }
    }
    __syncthreads();                                   // B8: h1 visible (both s)

    // ================= FFN (two K=256 rounds; FFN2 shares weights) ===========
    f32x4 fa[2][4];   // [s][{00,01,10,11}]
#pragma unroll
    for (int s = 0; s < 2; s++)
#pragma unroll
        for (int q = 0; q < 4; q++) fa[s][q] = f32x4{0.f,0.f,0.f,0.f};
    const int col0 = wave * 32 + lh, col1 = col0 + 16;
#pragma unroll
    for (int r = 0; r < 2; r++) {
        // ---- FFN1 per s: 4 column-tiles per wave -> s_m(s) ----
#pragma unroll
        for (int s = 0; s < 2; s++) {
            bf16x8 ah[2][4];
#pragma unroll
            for (int mt = 0; mt < 2; mt++)
#pragma unroll
                for (int kk = 0; kk < 4; kk++)
                    ah[mt][kk] = *(const bf16x8*)(SH(s) + (mt * 16 + lh) * 136 + kk * 32 + lg * 8);
            float b1v[4];
#pragma unroll
            for (int j = 0; j < 4; j++) b1v[j] = b1[(r * 16 + wave * 4 + j) * 16 + lh];
#pragma unroll
            for (int j = 0; j < 4; j++) {
                bf16x8 bw[4];
                {
                    const int nt = (r * 16 + wave * 4 + j) * 16 + lh;
#pragma unroll
                    for (int kk = 0; kk < 4; kk++)
                        bw[kk] = *(const bf16x8*)(w1_bf + (size_t)nt * 128 + kk * 32 + lg * 8);
                }
                f32x4 a0 = {0.f,0.f,0.f,0.f}, a1 = {0.f,0.f,0.f,0.f};
                PRIO_HI();
#pragma unroll
                for (int kk = 0; kk < 4; kk++) {
                    a0 = MFMA(ah[0][kk], bw[kk], a0);
                    a1 = MFMA(ah[1][kk], bw[kk], a1);
                }
                PRIO_LO();
                const float bias = b1v[j];
                const int cl = (wave * 4 + j) * 16 + lh;
                const int r0 = lg * 4;
#pragma unroll
                for (int i = 0; i < 4; i++) {
                    SM(s)[(r0 + i) * 260 + cl]      = f2bf_hw(fmaxf(a0[i] + bias, 0.f));
                    SM(s)[(16 + r0 + i) * 260 + cl] = f2bf_hw(fmaxf(a1[i] + bias, 0.f));
                }
            }
        }
        __syncthreads();                               // B9(r): f1 visible (both s)
        // ---- FFN2: shared w2 slices, 2 chains per load ----
#pragma unroll
        for (int kk = 0; kk < 8; kk++) {
            bf16x8 wp0 = *(const bf16x8*)(w2_bf + (size_t)col0 * 512 + r * 256 + kk * 32 + lg * 8);
            bf16x8 wp1 = *(const bf16x8*)(w2_bf + (size_t)col1 * 512 + r * 256 + kk * 32 + lg * 8);
            PRIO_HI();
#pragma unroll
            for (int s = 0; s < 2; s++) {
                bf16x8 a0 = *(const bf16x8*)(SM(s) + lh * 260 + kk * 32 + lg * 8);
                bf16x8 a1 = *(const bf16x8*)(SM(s) + (16 + lh) * 260 + kk * 32 + lg * 8);
                fa[s][0] = MFMA(a0, wp0, fa[s][0]);
                fa[s][1] = MFMA(a1, wp0, fa[s][1]);
                fa[s][2] = MFMA(a0, wp1, fa[s][2]);
                fa[s][3] = MFMA(a1, wp1, fa[s][3]);
            }
            PRIO_LO();
        }
        __syncthreads();                               // B10(r): f1 reads done
    }
    // ---- f2 -> s_mf(s) (fp32, stride 130) ----
    {
        const float bi0 = b2[col0], bi1 = b2[col1];
#pragma unroll
        for (int s = 0; s < 2; s++) {
#pragma unroll
            for (int i = 0; i < 4; i++) {
                SMF(s)[(lg * 4 + i) * 130 + col0]      = fa[s][0][i] + bi0;
                SMF(s)[(16 + lg * 4 + i) * 130 + col0] = fa[s][1][i] + bi0;
                SMF(s)[(lg * 4 + i) * 130 + col1]      = fa[s][2][i] + bi1;
                SMF(s)[(16 + lg * 4 + i) * 130 + col1] = fa[s][3][i] + bi1;
            }
        }
    }
    __syncthreads();                                   // B11: f2 visible

    // ================= LN2 + out + h2 -> s_h(s), per s =======================
    {
        float g[16], be[16];
        {
            const float4* pg = (const float4*)(ln2g + ds);
            const float4* pb = (const float4*)(ln2b + ds);
#pragma unroll
            for (int q = 0; q < 4; q++) {
                float4 vg = pg[q], vb = pb[q];
                g[4*q]=vg.x; g[4*q+1]=vg.y; g[4*q+2]=vg.z; g[4*q+3]=vg.w;
                be[4*q]=vb.x; be[4*q+1]=vb.y; be[4*q+2]=vb.z; be[4*q+3]=vb.w;
            }
        }
#pragma unroll
        for (int s = 0; s < 2; s++) {
            float t[16]; float sum = 0.f;
#pragma unroll
            for (int i = 0; i < 16; i++) {
                t[i] = bf2f((uint32)SH(s)[l * 136 + ds + i]) + SMF(s)[l * 130 + ds + i];
                sum += t[i];
            }
            sum += __shfl_xor(sum, 1); sum += __shfl_xor(sum, 2); sum += __shfl_xor(sum, 4);
            float mean = sum * (1.f / 128.f);
            float vs = 0.f;
#pragma unroll
            for (int i = 0; i < 16; i++) { float d = t[i] - mean; vs += d * d; }
            vs += __shfl_xor(vs, 1); vs += __shfl_xor(vs, 2); vs += __shfl_xor(vs, 4);
            float rs = rsqrtf(vs * (1.f / 128.f) + 1e-5f);
            float h2v[16];
#pragma unroll
            for (int i = 0; i < 16; i++)
                h2v[i] = (t[i] - mean) * rs * g[i] + be[i];
            float4* po = (float4*)(out_xt + (size_t)(n0 + s) * 4096 + tid * 16);
#pragma unroll
            for (int q = 0; q < 4; q++)
                po[q] = make_float4(h2v[4 * q], h2v[4 * q + 1], h2v[4 * q + 2], h2v[4 * q + 3]);
            store16bf(SH(s) + l * 136 + ds, h2v);      // own addrs
        }
    }
    __syncthreads();                                   // B12: h2 visible

    // ================= GCN weight GEMM (shared weights) ======================
    {
        bf16x8 wb[2][4];
#pragma unroll
        for (int j = 0; j < 2; j++)
#pragma unroll
            for (int kk = 0; kk < 4; kk++)
                wb[j][kk] = *(const bf16x8*)(wg_bf + (size_t)((wave * 2 + j) * 16 + lh) * 128 + kk * 32 + lg * 8);
#pragma unroll
        for (int s = 0; s < 2; s++) {
            bf16x8 ag[2][4];
#pragma unroll
            for (int mt = 0; mt < 2; mt++)
#pragma unroll
                for (int kk = 0; kk < 4; kk++)
                    ag[mt][kk] = *(const bf16x8*)(SH(s) + (mt * 16 + lh) * 136 + kk * 32 + lg * 8);
            ushort_t* hp = hh + (size_t)(n0 + s) * 4096;
#pragma unroll
            for (int j = 0; j < 2; j++) {
                f32x4 a0 = {0.f,0.f,0.f,0.f}, a1 = {0.f,0.f,0.f,0.f};
                PRIO_HI();
#pragma unroll
                for (int kk = 0; kk < 4; kk++) {
                    a0 = MFMA(ag[0][kk], wb[j][kk], a0);
                    a1 = MFMA(ag[1][kk], wb[j][kk], a1);
                }
                PRIO_LO();
                const int col = (wave * 2 + j) * 16 + lh;
                const int r0 = lg * 4;
#pragma unroll
                for (int i = 0; i < 4; i++) {
                    hp[(r0 + i) * 128 + col]      = f2bf_hw(a0[i]);
                    hp[(16 + r0 + i) * 128 + col] = f2bf_hw(a1[i]);
                }
            }
        }
    }
#undef SH
#undef SVT
#undef SM
#undef SMF
}

// One block per node; DUAL-CHAIN edge loop: 2 rows in flight per iteration,
// next pair's indices/weights prefetched during the accumulate.
__global__ __launch_bounds__(256)
void k_gather(const int* __restrict__ ei, const float* __restrict__ ew,
              const float* __restrict__ deg, const int* __restrict__ offs,
              const int* __restrict__ count, const int* __restrict__ elist,
              const ushort_t* __restrict__ hh, const float* __restrict__ gcn_b,
              float* __restrict__ out)
{
    const int node = blockIdx.x;
    const int b = node >> 10, i = node & 1023;
    const int tid = threadIdx.x;
    const float dcol = rsqrtf(deg[node]);
    const int off = offs[node], cnt = count[node];
    const ushort_t* hhb = hh + ((size_t)b * KDIM) * 4096;
    const int* elb = elist + (size_t)b * EDIM;
    const int* eib = ei + (size_t)b * 2 * EDIM;
    const float* ewb = ew + (size_t)b * EDIM;
    const float* degb = deg + b * KDIM;

    float acc[16];
    {
        const uint4* ph = (const uint4*)(hhb + (size_t)i * 4096 + tid * 16);
        uint4 a = ph[0], bb = ph[1];
        float tmp[16]; unpack8(a, tmp); unpack8(bb, tmp + 8);
        float nrm = dcol * dcol;
#pragma unroll
        for (int k = 0; k < 16; k++) acc[k] = tmp[k] * nrm;
    }
    if (cnt > 0) {
        int rowA, rowB = 0; float wA, wB = 0.f;
        {
            int eA = elb[off];
            rowA = eib[eA]; wA = ewb[eA];
            if (cnt > 1) { int eB = elb[off + 1]; rowB = eib[eB]; wB = ewb[eB]; }
        }
        for (int t = 0; t < cnt; t += 2) {
            const bool hasB = (t + 1 < cnt);
            const uint4* pA = (const uint4*)(hhb + (size_t)rowA * 4096 + tid * 16);
            uint4 a0 = pA[0], a1 = pA[1];
            uint4 b0 = make_uint4(0, 0, 0, 0), b1 = make_uint4(0, 0, 0, 0);
            if (hasB) {
                const uint4* pB = (const uint4*)(hhb + (size_t)rowB * 4096 + tid * 16);
                b0 = pB[0]; b1 = pB[1];
            }
            float nA = rsqrtf(degb[rowA]) * wA * dcol;
            float nB = hasB ? rsqrtf(degb[rowB]) * wB * dcol : 0.f;
            int rA2 = 0, rB2 = 0; float wA2 = 0.f, wB2 = 0.f;
            if (t + 2 < cnt) { int e = elb[off + t + 2]; rA2 = eib[e]; wA2 = ewb[e]; }
            if (t + 3 < cnt) { int e = elb[off + t + 3]; rB2 = eib[e]; wB2 = ewb[e]; }
            float tA[16]; unpack8(a0, tA); unpack8(a1, tA + 8);
#pragma unroll
            for (int k = 0; k < 16; k++) acc[k] += tA[k] * nA;
            float tB[16]; unpack8(b0, tB); unpack8(b1, tB + 8);
#pragma unroll
            for (int k = 0; k < 16; k++) acc[k] += tB[k] * nB;
            rowA = rA2; wA = wA2; rowB = rB2; wB = wB2;
        }
    }
    const int d0 = (tid * 16) & 127;
    float4* po = (float4*)(out + (size_t)node * 4096 + tid * 16);
#pragma unroll
    for (int q = 0; q < 4; q++) {
        float4 xo = po[q];
        xo.x += acc[4 * q]     + gcn_b[d0 + 4 * q];
        xo.y += acc[4 * q + 1] + gcn_b[d0 + 4 * q + 1];
        xo.z += acc[4 * q + 2] + gcn_b[d0 + 4 * q + 2];
        xo.w += acc[4 * q + 3] + gcn_b[d0 + 4 * q + 3];
        po[q] = xo;
    }
}

// ---------------------------------------------------------------------------
extern "C" void kernel_launch(void* const* d_in, const int* in_sizes, int n_in,
                              void* d_out, int out_size, void* d_ws, size_t ws_size,
                              hipStream_t stream) {
    const float* x     = (const float*)d_in[0];
    const int*   ei    = (const int*)d_in[1];
    const float* ew    = (const float*)d_in[2];
    const float* w_qkv = (const float*)d_in[3];
    const float* b_qkv = (const float*)d_in[4];
    const float* w_out = (const float*)d_in[5];
    const float* b_out = (const float*)d_in[6];
    const float* w1    = (const float*)d_in[7];
    const float* b1    = (const float*)d_in[8];
    const float* w2    = (const float*)d_in[9];
    const float* b2    = (const float*)d_in[10];
    const float* ln1g  = (const float*)d_in[11];
    const float* ln1b  = (const float*)d_in[12];
    const float* ln2g  = (const float*)d_in[13];
    const float* ln2b  = (const float*)d_in[14];
    const float* gcnw  = (const float*)d_in[15];
    const float* gcnb  = (const float*)d_in[16];
    float* out = (float*)d_out;

    // ws layout (bytes): weights 425984 | deg/count/offs/cursor 4x16384 | elist 262144 | hh 33554432
    char* ws = (char*)d_ws;
    ushort_t* wbf   = (ushort_t*)ws;
    ushort_t* wq_bf = wbf;
    ushort_t* wo_bf = wbf + 49152;
    ushort_t* w1_bf = wbf + 65536;
    ushort_t* w2_bf = wbf + 131072;
    ushort_t* wg_bf = wbf + 196608;
    float*    deg   = (float*)(ws + 425984);
    int*      count = (int*)(ws + 442368);
    int*      offs  = (int*)(ws + 458752);
    int*      elist = (int*)(ws + 491520);
    ushort_t* hh    = (ushort_t*)(ws + 753664);

    k_prep<<<(NWCVT + 255) / 256, 256, 0, stream>>>(w_qkv, w_out, w1, w2, gcnw, wbf);
    k_graph<<<BDIM, 1024, 0, stream>>>(ei, ew, deg, count, offs, elist);
    k_transformer<<<NSEQ / 2, 256, 0, stream>>>(x, wq_bf, b_qkv, wo_bf, b_out,
                                                w1_bf, b1, w2_bf, b2, wg_bf,
                                                ln1g, ln1b, ln2g, ln2b, out, hh);
    k_gather<<<NSEQ, 256, 0, stream>>>(ei, ew, deg, offs, count, elist, hh, gcnb, out);
}

// Round 20
// 291.077 us; speedup vs baseline: 1.0669x; 1.0669x over previous
//
#include <hip/hip_runtime.h>
#include <hip/hip_bf16.h>

// Problem constants
#define BDIM 4
#define KDIM 1024
#define EDIM 16384
#define NSEQ (BDIM * KDIM)   // 4096
#define REG  25856           // per-sequence LDS region stride (bytes)
#define MOFF 9216            // s_m offset within region (after s_vt [128][36])

typedef unsigned short ushort_t;
typedef unsigned int   uint32;

typedef __bf16 bf16x8 __attribute__((ext_vector_type(8)));
typedef float  f32x4  __attribute__((ext_vector_type(4)));

#define MFMA(A, B, C) __builtin_amdgcn_mfma_f32_16x16x32_bf16((A), (B), (C), 0, 0, 0)
#define PRIO_HI() __builtin_amdgcn_s_setprio(1)
#define PRIO_LO() __builtin_amdgcn_s_setprio(0)

__device__ __forceinline__ float bf2f(uint32 u) {
    union { uint32 i; float f; } v; v.i = u << 16; return v.f;
}
__device__ __forceinline__ ushort_t f2bf(float f) {
    union { float f; uint32 i; } v; v.f = f;
    uint32 r = (v.i + 0x7fffu + ((v.i >> 16) & 1u)) >> 16;
    return (ushort_t)r;
}
// hardware packed cvt: {lo=bf16(a), hi=bf16(b)}, RNE
__device__ __forceinline__ uint32 cvtpk(float a, float b) {
    uint32 r;
    asm("v_cvt_pk_bf16_f32 %0, %1, %2" : "=v"(r) : "v"(a), "v"(b));
    return r;
}
__device__ __forceinline__ ushort_t f2bf_hw(float f) { return (ushort_t)cvtpk(f, f); }

__device__ __forceinline__ void unpack8(uint4 v, float* dst) {
    const uint32* pv = (const uint32*)&v;
#pragma unroll
    for (int q = 0; q < 4; q++) {
        uint32 w = pv[q];
        dst[2 * q]     = bf2f(w & 0xffffu);
        dst[2 * q + 1] = bf2f(w >> 16);
    }
}
// pack 16 floats -> 16 bf16 (32B) at p (16B-aligned)
__device__ __forceinline__ void store16bf(ushort_t* p, const float* v) {
    uint32 w[8];
#pragma unroll
    for (int q = 0; q < 8; q++) w[q] = cvtpk(v[2 * q], v[2 * q + 1]);
    ((uint4*)p)[0] = make_uint4(w[0], w[1], w[2], w[3]);
    ((uint4*)p)[1] = make_uint4(w[4], w[5], w[6], w[7]);
}

// ---------------------------------------------------------------------------
// Weight pre-conversion fp32 -> bf16 into ws (+ fused deg/count init):
//   wqkv [384][128] @0 | wout [128][128] @49152 | w1 [512][128] @65536
//   w2 [128][512] @131072 | gcnw [128][128] @196608   (elements)
// ---------------------------------------------------------------------------
#define NWCVT 212992
__global__ void k_prep(const float* __restrict__ wq, const float* __restrict__ wo,
                       const float* __restrict__ w1, const float* __restrict__ w2,
                       const float* __restrict__ wg, ushort_t* __restrict__ dst,
                       float* __restrict__ deg, int* __restrict__ count) {
    int i = blockIdx.x * 256 + threadIdx.x;
    if (i >= NWCVT) return;
    if (i < BDIM * KDIM) { deg[i] = 1.0f; count[i] = 0; }   // fused k_init
    float v;
    if      (i <  49152) v = wq[i];
    else if (i <  65536) v = wo[i - 49152];
    else if (i < 131072) v = w1[i - 65536];
    else if (i < 196608) v = w2[i - 131072];
    else                 v = wg[i - 196608];
    dst[i] = f2bf(v);
}

// ---------------------------------------------------------------------------
// Fused transformer layer (session optimum): 2 seq/block, shared-weight
// QKV/W_out/FFN2/GCN, barrier-free striped attention, 12 barriers/block,
// T5 s_setprio around MFMA clusters (also cut VGPR 120->84 -> 3 blocks/CU).
// NO launch_bounds min-waves (pinned miscompile r7/r8).
// LDS 2 x 25856 = 51712 B.
// Region: s_h[32][136]<alias>s_vt[128][36] @0; s_m[32][260]|s_mf[32][130] @9216.
// ---------------------------------------------------------------------------
__global__ __launch_bounds__(256)
void k_transformer(const float* __restrict__ x,
                   const ushort_t* __restrict__ wq_bf, const float* __restrict__ b_qkv,
                   const ushort_t* __restrict__ wo_bf, const float* __restrict__ b_out,
                   const ushort_t* __restrict__ w1_bf, const float* __restrict__ b1,
                   const ushort_t* __restrict__ w2_bf, const float* __restrict__ b2,
                   const ushort_t* __restrict__ wg_bf,
                   const float* __restrict__ ln1g, const float* __restrict__ ln1b,
                   const float* __restrict__ ln2g, const float* __restrict__ ln2b,
                   float* __restrict__ out_xt, ushort_t* __restrict__ hh)
{
    const int n0   = blockIdx.x * 2;
    const int tid  = threadIdx.x;
    const int wave = tid >> 6;
    const int lane = tid & 63;
    const int lh   = lane & 15;      // M-row / N-col within 16x16 tile
    const int lg   = lane >> 4;      // k-group (8 elems each)
    const int l    = tid >> 3;       // per-thread row (LN phases)
    const int ds   = (tid & 7) * 16;

    __shared__ __align__(16) char smem[2 * REG];
#define SH(s)  ((ushort_t*)(smem + (s) * REG))
#define SVT(s) ((ushort_t*)(smem + (s) * REG))
#define SM(s)  ((ushort_t*)(smem + (s) * REG + MOFF))
#define SMF(s) ((float*)(smem + (s) * REG + MOFF))

    // ---- load h0 for both sequences -> s_h(s) (bf16) ----
#pragma unroll
    for (int s = 0; s < 2; s++) {
        const float4* px = (const float4*)(x + (size_t)(n0 + s) * 4096 + tid * 16);
        float h0[16];
#pragma unroll
        for (int q = 0; q < 4; q++) {
            float4 v = px[q];
            h0[4 * q] = v.x; h0[4 * q + 1] = v.y; h0[4 * q + 2] = v.z; h0[4 * q + 3] = v.w;
        }
        store16bf(SH(s) + l * 136 + ds, h0);
    }
    __syncthreads();                                   // B1

    // ================= QKV (shared weights, 2 chains per load) ===============
    {
        bf16x8 af[2][2][4];   // [s][mt][kk]
#pragma unroll
        for (int s = 0; s < 2; s++)
#pragma unroll
            for (int mt = 0; mt < 2; mt++)
#pragma unroll
                for (int kk = 0; kk < 4; kk++)
                    af[s][mt][kk] = *(const bf16x8*)(SH(s) + (mt * 16 + lh) * 136 + kk * 32 + lg * 8);
        __syncthreads();                               // B2: s_h dead; V^T may write region0

        const int ntb = wave * 6;
        float biasv[6];
#pragma unroll
        for (int j = 0; j < 6; j++) biasv[j] = b_qkv[(ntb + j) * 16 + lh];
#pragma unroll
        for (int j = 0; j < 6; j++) {
            bf16x8 bw[4];
#pragma unroll
            for (int kk = 0; kk < 4; kk++)
                bw[kk] = *(const bf16x8*)(wq_bf + (size_t)((ntb + j) * 16 + lh) * 128 + kk * 32 + lg * 8);
            f32x4 A[2][2];
#pragma unroll
            for (int s = 0; s < 2; s++) { A[s][0] = f32x4{0.f,0.f,0.f,0.f}; A[s][1] = f32x4{0.f,0.f,0.f,0.f}; }
            PRIO_HI();
#pragma unroll
            for (int kk = 0; kk < 4; kk++) {
#pragma unroll
                for (int s = 0; s < 2; s++) {
                    A[s][0] = MFMA(af[s][0][kk], bw[kk], A[s][0]);
                    A[s][1] = MFMA(af[s][1][kk], bw[kk], A[s][1]);
                }
            }
            PRIO_LO();
            const int nt  = ntb + j;
            const int col = nt * 16 + lh;
            const float bias = biasv[j];
#pragma unroll
            for (int s = 0; s < 2; s++) {
                if (nt < 16) {          // Q (cols 0-127) | K (cols 128-255)
                    const int r0 = lg * 4;
#pragma unroll
                    for (int i = 0; i < 4; i++) {
                        SM(s)[(r0 + i) * 260 + col]      = f2bf_hw(A[s][0][i] + bias);
                        SM(s)[(16 + r0 + i) * 260 + col] = f2bf_hw(A[s][1][i] + bias);
                    }
                } else {                // V -> transposed s_vt[dh][key] (region0)
                    const int vc = col - 256;
                    uint32 p01 = cvtpk(A[s][0][0] + bias, A[s][0][1] + bias);
                    uint32 p23 = cvtpk(A[s][0][2] + bias, A[s][0][3] + bias);
                    uint32 q01 = cvtpk(A[s][1][0] + bias, A[s][1][1] + bias);
                    uint32 q23 = cvtpk(A[s][1][2] + bias, A[s][1][3] + bias);
                    *(uint32*)&SVT(s)[vc * 36 + lg * 4]          = p01;
                    *(uint32*)&SVT(s)[vc * 36 + lg * 4 + 2]      = p23;
                    *(uint32*)&SVT(s)[vc * 36 + 16 + lg * 4]     = q01;
                    *(uint32*)&SVT(s)[vc * 36 + 16 + lg * 4 + 2] = q23;
                }
            }
        }
    }
    __syncthreads();                                   // B3: Q,K,V^T visible (both s)

    // ============ attention: BARRIER-FREE per-wave striped section ===========
    {
        // W_out weights + biases loaded ONCE, early (consumed after B6)
        bf16x8 wbo[2][4];
#pragma unroll
        for (int j = 0; j < 2; j++)
#pragma unroll
            for (int kk = 0; kk < 4; kk++)
                wbo[j][kk] = *(const bf16x8*)(wo_bf + (size_t)((wave * 2 + j) * 16 + lh) * 128 + kk * 32 + lg * 8);
        float bo0 = b_out[(wave * 2 + 0) * 16 + lh];
        float bo1 = b_out[(wave * 2 + 1) * 16 + lh];

#pragma unroll
        for (int s = 0; s < 2; s++) {
            // ---- QK^T both heads (must precede P: P(hd0) overwrites Q(hd1)) --
            f32x4 sA[2][2][2];   // [hd][mt][nt]
            bf16x8 bz = {};
            PRIO_HI();
#pragma unroll
            for (int hd = 0; hd < 2; hd++) {
                const int h8 = wave * 2 + hd;
#pragma unroll
                for (int mt = 0; mt < 2; mt++) {
                    bf16x8 aq = *(const bf16x8*)(SM(s) + (mt * 16 + lh) * 260 + h8 * 16 + (lg & 1) * 8);
#pragma unroll
                    for (int nt = 0; nt < 2; nt++) {
                        bf16x8 bk = bz;
                        if (lg < 2)
                            bk = *(const bf16x8*)(SM(s) + (nt * 16 + lh) * 260 + 128 + h8 * 16 + lg * 8);
                        f32x4 z = {0.f,0.f,0.f,0.f};
                        sA[hd][mt][nt] = MFMA(aq, bk, z);
                    }
                }
            }
            PRIO_LO();
            // ---- softmax + P into own stripes (wave-local) ----
#pragma unroll
            for (int hd = 0; hd < 2; hd++) {
                const int cb = hd ? (128 + wave * 32) : (wave * 32);
#pragma unroll
                for (int mt = 0; mt < 2; mt++) {
#pragma unroll
                    for (int i = 0; i < 4; i++) {
                        float e0 = __expf(sA[hd][mt][0][i] * 0.25f);
                        float e1 = __expf(sA[hd][mt][1][i] * 0.25f);
                        float sm = e0 + e1;
                        sm += __shfl_xor(sm, 1); sm += __shfl_xor(sm, 2);
                        sm += __shfl_xor(sm, 4); sm += __shfl_xor(sm, 8);
                        float inv = 1.0f / sm;
                        const int row = mt * 16 + lg * 4 + i;
                        SM(s)[row * 260 + cb + lh]      = f2bf_hw(e0 * inv);
                        SM(s)[row * 260 + cb + 16 + lh] = f2bf_hw(e1 * inv);
                    }
                }
            }
            // ---- PV -> O into own col stripe (wave-local) ----
            PRIO_HI();
#pragma unroll
            for (int hd = 0; hd < 2; hd++) {
                const int h8 = wave * 2 + hd;
                const int cb = hd ? (128 + wave * 32) : (wave * 32);
                bf16x8 bv = *(const bf16x8*)(SVT(s) + (h8 * 16 + lh) * 36 + lg * 8);
#pragma unroll
                for (int mt = 0; mt < 2; mt++) {
                    bf16x8 ap = *(const bf16x8*)(SM(s) + (mt * 16 + lh) * 260 + cb + lg * 8);
                    f32x4 z = {0.f,0.f,0.f,0.f};
                    f32x4 o = MFMA(ap, bv, z);
                    const int r0 = mt * 16 + lg * 4, c = h8 * 16 + lh;
#pragma unroll
                    for (int i = 0; i < 4; i++)
                        SM(s)[(r0 + i) * 260 + c] = f2bf_hw(o[i]);
                }
            }
            PRIO_LO();
        }
        __syncthreads();                               // B6: O complete (both s)
        // W_out -> u (bf16, region0(s)); shared wbo, 2 chains
#pragma unroll
        for (int s = 0; s < 2; s++) {
            bf16x8 af2[2][4];
#pragma unroll
            for (int mt = 0; mt < 2; mt++)
#pragma unroll
                for (int kk = 0; kk < 4; kk++)
                    af2[mt][kk] = *(const bf16x8*)(SM(s) + (mt * 16 + lh) * 260 + kk * 32 + lg * 8);
#pragma unroll
            for (int j = 0; j < 2; j++) {
                f32x4 a0 = {0.f,0.f,0.f,0.f}, a1 = {0.f,0.f,0.f,0.f};
                PRIO_HI();
#pragma unroll
                for (int kk = 0; kk < 4; kk++) {
                    a0 = MFMA(af2[0][kk], wbo[j][kk], a0);
                    a1 = MFMA(af2[1][kk], wbo[j][kk], a1);
                }
                PRIO_LO();
                const int col = (wave * 2 + j) * 16 + lh;
                const float bias = j ? bo1 : bo0;
#pragma unroll
                for (int i = 0; i < 4; i++) {
                    SH(s)[(lg * 4 + i) * 136 + col]      = f2bf_hw(a0[i] + bias);
                    SH(s)[(16 + lg * 4 + i) * 136 + col] = f2bf_hw(a1[i] + bias);
                }
            }
        }
        __syncthreads();                               // B7: u visible (both s)
        // LN1: h1 = LN(h0 + u) -> s_h(s), both s (gamma/beta loaded once)
        {
            float g[16], be[16];
            {
                const float4* pg = (const float4*)(ln1g + ds);
                const float4* pb = (const float4*)(ln1b + ds);
#pragma unroll
                for (int q = 0; q < 4; q++) {
                    float4 vg = pg[q], vb = pb[q];
                    g[4*q]=vg.x; g[4*q+1]=vg.y; g[4*q+2]=vg.z; g[4*q+3]=vg.w;
                    be[4*q]=vb.x; be[4*q+1]=vb.y; be[4*q+2]=vb.z; be[4*q+3]=vb.w;
                }
            }
#pragma unroll
            for (int s = 0; s < 2; s++) {
                const float4* px = (const float4*)(x + (size_t)(n0 + s) * 4096 + tid * 16);
                float4 hx0 = px[0], hx1 = px[1], hx2 = px[2], hx3 = px[3];
                float h0v[16];
                { float4 v = hx0; h0v[0]=v.x; h0v[1]=v.y; h0v[2]=v.z; h0v[3]=v.w; }
                { float4 v = hx1; h0v[4]=v.x; h0v[5]=v.y; h0v[6]=v.z; h0v[7]=v.w; }
                { float4 v = hx2; h0v[8]=v.x; h0v[9]=v.y; h0v[10]=v.z; h0v[11]=v.w; }
                { float4 v = hx3; h0v[12]=v.x; h0v[13]=v.y; h0v[14]=v.z; h0v[15]=v.w; }
                float t[16]; float sum = 0.f;
#pragma unroll
                for (int i = 0; i < 16; i++) {
                    t[i] = h0v[i] + bf2f((uint32)SH(s)[l * 136 + ds + i]);
                    sum += t[i];
                }
                sum += __shfl_xor(sum, 1); sum += __shfl_xor(sum, 2); sum += __shfl_xor(sum, 4);
                float mean = sum * (1.f / 128.f);
                float vs = 0.f;
#pragma unroll
                for (int i = 0; i < 16; i++) { float d = t[i] - mean; vs += d * d; }
                vs += __shfl_xor(vs, 1); vs += __shfl_xor(vs, 2); vs += __shfl_xor(vs, 4);
                float rs = rsqrtf(vs * (1.f / 128.f) + 1e-5f);
                float h1v[16];
#pragma unroll
                for (int i = 0; i < 16; i++)
                    h1v[i] = (t[i] - mean) * rs * g[i] + be[i];
                store16bf(SH(s) + l * 136 + ds, h1v);  // own addrs
            }
        }
    }
    __syncthreads();                                   // B8: h1 visible (both s)

    // ================= FFN (two K=256 rounds; FFN2 shares weights) ===========
    f32x4 fa[2][4];   // [s][{00,01,10,11}]
#pragma unroll
    for (int s = 0; s < 2; s++)
#pragma unroll
        for (int q = 0; q < 4; q++) fa[s][q] = f32x4{0.f,0.f,0.f,0.f};
    const int col0 = wave * 32 + lh, col1 = col0 + 16;
#pragma unroll
    for (int r = 0; r < 2; r++) {
        // ---- FFN1 per s: 4 column-tiles per wave -> s_m(s) ----
#pragma unroll
        for (int s = 0; s < 2; s++) {
            bf16x8 ah[2][4];
#pragma unroll
            for (int mt = 0; mt < 2; mt++)
#pragma unroll
                for (int kk = 0; kk < 4; kk++)
                    ah[mt][kk] = *(const bf16x8*)(SH(s) + (mt * 16 + lh) * 136 + kk * 32 + lg * 8);
            float b1v[4];
#pragma unroll
            for (int j = 0; j < 4; j++) b1v[j] = b1[(r * 16 + wave * 4 + j) * 16 + lh];
#pragma unroll
            for (int j = 0; j < 4; j++) {
                bf16x8 bw[4];
                {
                    const int nt = (r * 16 + wave * 4 + j) * 16 + lh;
#pragma unroll
                    for (int kk = 0; kk < 4; kk++)
                        bw[kk] = *(const bf16x8*)(w1_bf + (size_t)nt * 128 + kk * 32 + lg * 8);
                }
                f32x4 a0 = {0.f,0.f,0.f,0.f}, a1 = {0.f,0.f,0.f,0.f};
                PRIO_HI();
#pragma unroll
                for (int kk = 0; kk < 4; kk++) {
                    a0 = MFMA(ah[0][kk], bw[kk], a0);
                    a1 = MFMA(ah[1][kk], bw[kk], a1);
                }
                PRIO_LO();
                const float bias = b1v[j];
                const int cl = (wave * 4 + j) * 16 + lh;
                const int r0 = lg * 4;
#pragma unroll
                for (int i = 0; i < 4; i++) {
                    SM(s)[(r0 + i) * 260 + cl]      = f2bf_hw(fmaxf(a0[i] + bias, 0.f));
                    SM(s)[(16 + r0 + i) * 260 + cl] = f2bf_hw(fmaxf(a1[i] + bias, 0.f));
                }
            }
        }
        __syncthreads();                               // B9(r): f1 visible (both s)
        // ---- FFN2: shared w2 slices, 2 chains per load ----
#pragma unroll
        for (int kk = 0; kk < 8; kk++) {
            bf16x8 wp0 = *(const bf16x8*)(w2_bf + (size_t)col0 * 512 + r * 256 + kk * 32 + lg * 8);
            bf16x8 wp1 = *(const bf16x8*)(w2_bf + (size_t)col1 * 512 + r * 256 + kk * 32 + lg * 8);
            PRIO_HI();
#pragma unroll
            for (int s = 0; s < 2; s++) {
                bf16x8 a0 = *(const bf16x8*)(SM(s) + lh * 260 + kk * 32 + lg * 8);
                bf16x8 a1 = *(const bf16x8*)(SM(s) + (16 + lh) * 260 + kk * 32 + lg * 8);
                fa[s][0] = MFMA(a0, wp0, fa[s][0]);
                fa[s][1] = MFMA(a1, wp0, fa[s][1]);
                fa[s][2] = MFMA(a0, wp1, fa[s][2]);
                fa[s][3] = MFMA(a1, wp1, fa[s][3]);
            }
            PRIO_LO();
        }
        __syncthreads();                               // B10(r): f1 reads done
    }
    // ---- f2 -> s_mf(s) (fp32, stride 130) ----
    {
        const float bi0 = b2[col0], bi1 = b2[col1];
#pragma unroll
        for (int s = 0; s < 2; s++) {
#pragma unroll
            for (int i = 0; i < 4; i++) {
                SMF(s)[(lg * 4 + i) * 130 + col0]      = fa[s][0][i] + bi0;
                SMF(s)[(16 + lg * 4 + i) * 130 + col0] = fa[s][1][i] + bi0;
                SMF(s)[(lg * 4 + i) * 130 + col1]      = fa[s][2][i] + bi1;
                SMF(s)[(16 + lg * 4 + i) * 130 + col1] = fa[s][3][i] + bi1;
            }
        }
    }
    __syncthreads();                                   // B11: f2 visible

    // ================= LN2 + out + h2 -> s_h(s), per s =======================
    {
        float g[16], be[16];
        {
            const float4* pg = (const float4*)(ln2g + ds);
            const float4* pb = (const float4*)(ln2b + ds);
#pragma unroll
            for (int q = 0; q < 4; q++) {
                float4 vg = pg[q], vb = pb[q];
                g[4*q]=vg.x; g[4*q+1]=vg.y; g[4*q+2]=vg.z; g[4*q+3]=vg.w;
                be[4*q]=vb.x; be[4*q+1]=vb.y; be[4*q+2]=vb.z; be[4*q+3]=vb.w;
            }
        }
#pragma unroll
        for (int s = 0; s < 2; s++) {
            float t[16]; float sum = 0.f;
#pragma unroll
            for (int i = 0; i < 16; i++) {
                t[i] = bf2f((uint32)SH(s)[l * 136 + ds + i]) + SMF(s)[l * 130 + ds + i];
                sum += t[i];
            }
            sum += __shfl_xor(sum, 1); sum += __shfl_xor(sum, 2); sum += __shfl_xor(sum, 4);
            float mean = sum * (1.f / 128.f);
            float vs = 0.f;
#pragma unroll
            for (int i = 0; i < 16; i++) { float d = t[i] - mean; vs += d * d; }
            vs += __shfl_xor(vs, 1); vs += __shfl_xor(vs, 2); vs += __shfl_xor(vs, 4);
            float rs = rsqrtf(vs * (1.f / 128.f) + 1e-5f);
            float h2v[16];
#pragma unroll
            for (int i = 0; i < 16; i++)
                h2v[i] = (t[i] - mean) * rs * g[i] + be[i];
            float4* po = (float4*)(out_xt + (size_t)(n0 + s) * 4096 + tid * 16);
#pragma unroll
            for (int q = 0; q < 4; q++)
                po[q] = make_float4(h2v[4 * q], h2v[4 * q + 1], h2v[4 * q + 2], h2v[4 * q + 3]);
            store16bf(SH(s) + l * 136 + ds, h2v);      // own addrs
        }
    }
    __syncthreads();                                   // B12: h2 visible

    // ================= GCN weight GEMM (shared weights) ======================
    {
        bf16x8 wb[2][4];
#pragma unroll
        for (int j = 0; j < 2; j++)
#pragma unroll
            for (int kk = 0; kk < 4; kk++)
                wb[j][kk] = *(const bf16x8*)(wg_bf + (size_t)((wave * 2 + j) * 16 + lh) * 128 + kk * 32 + lg * 8);
#pragma unroll
        for (int s = 0; s < 2; s++) {
            bf16x8 ag[2][4];
#pragma unroll
            for (int mt = 0; mt < 2; mt++)
#pragma unroll
                for (int kk = 0; kk < 4; kk++)
                    ag[mt][kk] = *(const bf16x8*)(SH(s) + (mt * 16 + lh) * 136 + kk * 32 + lg * 8);
            ushort_t* hp = hh + (size_t)(n0 + s) * 4096;
#pragma unroll
            for (int j = 0; j < 2; j++) {
                f32x4 a0 = {0.f,0.f,0.f,0.f}, a1 = {0.f,0.f,0.f,0.f};
                PRIO_HI();
#pragma unroll
                for (int kk = 0; kk < 4; kk++) {
                    a0 = MFMA(ag[0][kk], wb[j][kk], a0);
                    a1 = MFMA(ag[1][kk], wb[j][kk], a1);
                }
                PRIO_LO();
                const int col = (wave * 2 + j) * 16 + lh;
                const int r0 = lg * 4;
#pragma unroll
                for (int i = 0; i < 4; i++) {
                    hp[(r0 + i) * 128 + col]      = f2bf_hw(a0[i]);
                    hp[(16 + r0 + i) * 128 + col] = f2bf_hw(a1[i]);
                }
            }
        }
    }
#undef SH
#undef SVT
#undef SM
#undef SMF
}

// ---------------------------------------------------------------------------
// GCN support kernels
// ---------------------------------------------------------------------------
__global__ void k_degcount(const int* __restrict__ ei, const float* __restrict__ ew,
                           float* deg, int* count) {
    int idx = blockIdx.x * 256 + threadIdx.x;
    if (idx >= BDIM * EDIM) return;
    int b = idx / EDIM, e = idx - b * EDIM;
    int col = ei[(size_t)b * 2 * EDIM + EDIM + e];
    float w = ew[(size_t)b * EDIM + e];
    atomicAdd(&deg[b * KDIM + col], w);
    atomicAdd(&count[b * KDIM + col], 1);
}

__global__ __launch_bounds__(1024)
void k_scan(const int* __restrict__ count, int* offs, int* cursor) {
    __shared__ int s[KDIM];
    int b = blockIdx.x, i = threadIdx.x;
    int c = count[b * KDIM + i];
    s[i] = c; __syncthreads();
#pragma unroll 1
    for (int off = 1; off < KDIM; off <<= 1) {
        int t = (i >= off) ? s[i - off] : 0;
        __syncthreads();
        s[i] += t;
        __syncthreads();
    }
    int excl = s[i] - c;
    offs[b * KDIM + i] = excl;
    cursor[b * KDIM + i] = excl;
}

__global__ void k_fill(const int* __restrict__ ei, int* cursor, int* elist) {
    int idx = blockIdx.x * 256 + threadIdx.x;
    if (idx >= BDIM * EDIM) return;
    int b = idx / EDIM, e = idx - b * EDIM;
    int col = ei[(size_t)b * 2 * EDIM + EDIM + e];
    int pos = atomicAdd(&cursor[b * KDIM + col], 1);
    elist[(size_t)b * EDIM + pos] = e;
}

// One block per node; DUAL-CHAIN edge loop: 2 rows in flight per iteration,
// next pair's indices/weights prefetched during the accumulate.
__global__ __launch_bounds__(256)
void k_gather(const int* __restrict__ ei, const float* __restrict__ ew,
              const float* __restrict__ deg, const int* __restrict__ offs,
              const int* __restrict__ count, const int* __restrict__ elist,
              const ushort_t* __restrict__ hh, const float* __restrict__ gcn_b,
              float* __restrict__ out)
{
    const int node = blockIdx.x;
    const int b = node >> 10, i = node & 1023;
    const int tid = threadIdx.x;
    const float dcol = rsqrtf(deg[node]);
    const int off = offs[node], cnt = count[node];
    const ushort_t* hhb = hh + ((size_t)b * KDIM) * 4096;
    const int* elb = elist + (size_t)b * EDIM;
    const int* eib = ei + (size_t)b * 2 * EDIM;
    const float* ewb = ew + (size_t)b * EDIM;
    const float* degb = deg + b * KDIM;

    float acc[16];
    {
        const uint4* ph = (const uint4*)(hhb + (size_t)i * 4096 + tid * 16);
        uint4 a = ph[0], bb = ph[1];
        float tmp[16]; unpack8(a, tmp); unpack8(bb, tmp + 8);
        float nrm = dcol * dcol;
#pragma unroll
        for (int k = 0; k < 16; k++) acc[k] = tmp[k] * nrm;
    }
    if (cnt > 0) {
        int rowA, rowB = 0; float wA, wB = 0.f;
        {
            int eA = elb[off];
            rowA = eib[eA]; wA = ewb[eA];
            if (cnt > 1) { int eB = elb[off + 1]; rowB = eib[eB]; wB = ewb[eB]; }
        }
        for (int t = 0; t < cnt; t += 2) {
            const bool hasB = (t + 1 < cnt);
            const uint4* pA = (const uint4*)(hhb + (size_t)rowA * 4096 + tid * 16);
            uint4 a0 = pA[0], a1 = pA[1];
            uint4 b0 = make_uint4(0, 0, 0, 0), b1 = make_uint4(0, 0, 0, 0);
            if (hasB) {
                const uint4* pB = (const uint4*)(hhb + (size_t)rowB * 4096 + tid * 16);
                b0 = pB[0]; b1 = pB[1];
            }
            float nA = rsqrtf(degb[rowA]) * wA * dcol;
            float nB = hasB ? rsqrtf(degb[rowB]) * wB * dcol : 0.f;
            int rA2 = 0, rB2 = 0; float wA2 = 0.f, wB2 = 0.f;
            if (t + 2 < cnt) { int e = elb[off + t + 2]; rA2 = eib[e]; wA2 = ewb[e]; }
            if (t + 3 < cnt) { int e = elb[off + t + 3]; rB2 = eib[e]; wB2 = ewb[e]; }
            float tA[16]; unpack8(a0, tA); unpack8(a1, tA + 8);
#pragma unroll
            for (int k = 0; k < 16; k++) acc[k] += tA[k] * nA;
            float tB[16]; unpack8(b0, tB); unpack8(b1, tB + 8);
#pragma unroll
            for (int k = 0; k < 16; k++) acc[k] += tB[k] * nB;
            rowA = rA2; wA = wA2; rowB = rB2; wB = wB2;
        }
    }
    const int d0 = (tid * 16) & 127;
    float4* po = (float4*)(out + (size_t)node * 4096 + tid * 16);
#pragma unroll
    for (int q = 0; q < 4; q++) {
        float4 xo = po[q];
        xo.x += acc[4 * q]     + gcn_b[d0 + 4 * q];
        xo.y += acc[4 * q + 1] + gcn_b[d0 + 4 * q + 1];
        xo.z += acc[4 * q + 2] + gcn_b[d0 + 4 * q + 2];
        xo.w += acc[4 * q + 3] + gcn_b[d0 + 4 * q + 3];
        po[q] = xo;
    }
}

// ---------------------------------------------------------------------------
extern "C" void kernel_launch(void* const* d_in, const int* in_sizes, int n_in,
                              void* d_out, int out_size, void* d_ws, size_t ws_size,
                              hipStream_t stream) {
    const float* x     = (const float*)d_in[0];
    const int*   ei    = (const int*)d_in[1];
    const float* ew    = (const float*)d_in[2];
    const float* w_qkv = (const float*)d_in[3];
    const float* b_qkv = (const float*)d_in[4];
    const float* w_out = (const float*)d_in[5];
    const float* b_out = (const float*)d_in[6];
    const float* w1    = (const float*)d_in[7];
    const float* b1    = (const float*)d_in[8];
    const float* w2    = (const float*)d_in[9];
    const float* b2    = (const float*)d_in[10];
    const float* ln1g  = (const float*)d_in[11];
    const float* ln1b  = (const float*)d_in[12];
    const float* ln2g  = (const float*)d_in[13];
    const float* ln2b  = (const float*)d_in[14];
    const float* gcnw  = (const float*)d_in[15];
    const float* gcnb  = (const float*)d_in[16];
    float* out = (float*)d_out;

    // ws layout (bytes): weights 425984 | deg/count/offs/cursor 4x16384 | elist 262144 | hh 33554432
    char* ws = (char*)d_ws;
    ushort_t* wbf   = (ushort_t*)ws;
    ushort_t* wq_bf = wbf;
    ushort_t* wo_bf = wbf + 49152;
    ushort_t* w1_bf = wbf + 65536;
    ushort_t* w2_bf = wbf + 131072;
    ushort_t* wg_bf = wbf + 196608;
    float*    deg   = (float*)(ws + 425984);
    int*      count = (int*)(ws + 442368);
    int*      offs  = (int*)(ws + 458752);
    int*      cursor= (int*)(ws + 475136);
    int*      elist = (int*)(ws + 491520);
    ushort_t* hh    = (ushort_t*)(ws + 753664);

    k_prep<<<(NWCVT + 255) / 256, 256, 0, stream>>>(w_qkv, w_out, w1, w2, gcnw, wbf, deg, count);
    k_transformer<<<NSEQ / 2, 256, 0, stream>>>(x, wq_bf, b_qkv, wo_bf, b_out,
                                                w1_bf, b1, w2_bf, b2, wg_bf,
                                                ln1g, ln1b, ln2g, ln2b, out, hh);
    k_degcount<<<256, 256, 0, stream>>>(ei, ew, deg, count);
    k_scan<<<BDIM, 1024, 0, stream>>>(count, offs, cursor);
    k_fill<<<256, 256, 0, stream>>>(ei, cursor, elist);
    k_gather<<<NSEQ, 256, 0, stream>>>(ei, ew, deg, offs, count, elist, hh, gcnb, out);
}

// Round 21
// 275.789 us; speedup vs baseline: 1.1260x; 1.0554x over previous
//
#include <hip/hip_runtime.h>
#include <hip/hip_bf16.h>

// Problem constants
#define BDIM 4
#define KDIM 1024
#define EDIM 16384
#define NSEQ (BDIM * KDIM)   // 4096
#define REG  25856           // per-sequence LDS region stride (bytes)
#define MOFF 9216            // s_m offset within region (after s_vt [128][36])

typedef unsigned short ushort_t;
typedef unsigned int   uint32;

typedef __bf16 bf16x8 __attribute__((ext_vector_type(8)));
typedef float  f32x4  __attribute__((ext_vector_type(4)));

#define MFMA(A, B, C) __builtin_amdgcn_mfma_f32_16x16x32_bf16((A), (B), (C), 0, 0, 0)
#define PRIO_HI() __builtin_amdgcn_s_setprio(1)
#define PRIO_LO() __builtin_amdgcn_s_setprio(0)

__device__ __forceinline__ float bf2f(uint32 u) {
    union { uint32 i; float f; } v; v.i = u << 16; return v.f;
}
__device__ __forceinline__ ushort_t f2bf(float f) {
    union { float f; uint32 i; } v; v.f = f;
    uint32 r = (v.i + 0x7fffu + ((v.i >> 16) & 1u)) >> 16;
    return (ushort_t)r;
}
// hardware packed cvt: {lo=bf16(a), hi=bf16(b)}, RNE
__device__ __forceinline__ uint32 cvtpk(float a, float b) {
    uint32 r;
    asm("v_cvt_pk_bf16_f32 %0, %1, %2" : "=v"(r) : "v"(a), "v"(b));
    return r;
}
__device__ __forceinline__ ushort_t f2bf_hw(float f) { return (ushort_t)cvtpk(f, f); }

__device__ __forceinline__ void unpack8(uint4 v, float* dst) {
    const uint32* pv = (const uint32*)&v;
#pragma unroll
    for (int q = 0; q < 4; q++) {
        uint32 w = pv[q];
        dst[2 * q]     = bf2f(w & 0xffffu);
        dst[2 * q + 1] = bf2f(w >> 16);
    }
}
// pack 16 floats -> 16 bf16 (32B) at p (16B-aligned)
__device__ __forceinline__ void store16bf(ushort_t* p, const float* v) {
    uint32 w[8];
#pragma unroll
    for (int q = 0; q < 8; q++) w[q] = cvtpk(v[2 * q], v[2 * q + 1]);
    ((uint4*)p)[0] = make_uint4(w[0], w[1], w[2], w[3]);
    ((uint4*)p)[1] = make_uint4(w[4], w[5], w[6], w[7]);
}

// ---------------------------------------------------------------------------
// Weight pre-conversion fp32 -> bf16 into ws (+ fused deg/count init):
//   wqkv [384][128] @0 | wout [128][128] @49152 | w1 [512][128] @65536
//   w2 [128][512] @131072 | gcnw [128][128] @196608   (elements)
// ---------------------------------------------------------------------------
#define NWCVT 212992
__global__ void k_prep(const float* __restrict__ wq, const float* __restrict__ wo,
                       const float* __restrict__ w1, const float* __restrict__ w2,
                       const float* __restrict__ wg, ushort_t* __restrict__ dst,
                       float* __restrict__ deg, int* __restrict__ count) {
    int i = blockIdx.x * 256 + threadIdx.x;
    if (i >= NWCVT) return;
    if (i < BDIM * KDIM) { deg[i] = 1.0f; count[i] = 0; }   // fused k_init
    float v;
    if      (i <  49152) v = wq[i];
    else if (i <  65536) v = wo[i - 49152];
    else if (i < 131072) v = w1[i - 65536];
    else if (i < 196608) v = w2[i - 131072];
    else                 v = wg[i - 196608];
    dst[i] = f2bf(v);
}

// ---------------------------------------------------------------------------
// Fused transformer layer (session optimum): 2 seq/block, shared-weight
// QKV/W_out/FFN2/GCN, barrier-free striped attention, 12 barriers/block,
// T5 s_setprio around MFMA clusters (also cut VGPR 120->84 -> 3 blocks/CU).
// NO launch_bounds min-waves (pinned miscompile r7/r8).
// LDS 2 x 25856 = 51712 B.
// Region: s_h[32][136]<alias>s_vt[128][36] @0; s_m[32][260]|s_mf[32][130] @9216.
// ---------------------------------------------------------------------------
__global__ __launch_bounds__(256)
void k_transformer(const float* __restrict__ x,
                   const ushort_t* __restrict__ wq_bf, const float* __restrict__ b_qkv,
                   const ushort_t* __restrict__ wo_bf, const float* __restrict__ b_out,
                   const ushort_t* __restrict__ w1_bf, const float* __restrict__ b1,
                   const ushort_t* __restrict__ w2_bf, const float* __restrict__ b2,
                   const ushort_t* __restrict__ wg_bf,
                   const float* __restrict__ ln1g, const float* __restrict__ ln1b,
                   const float* __restrict__ ln2g, const float* __restrict__ ln2b,
                   float* __restrict__ out_xt, ushort_t* __restrict__ hh)
{
    const int n0   = blockIdx.x * 2;
    const int tid  = threadIdx.x;
    const int wave = tid >> 6;
    const int lane = tid & 63;
    const int lh   = lane & 15;      // M-row / N-col within 16x16 tile
    const int lg   = lane >> 4;      // k-group (8 elems each)
    const int l    = tid >> 3;       // per-thread row (LN phases)
    const int ds   = (tid & 7) * 16;

    __shared__ __align__(16) char smem[2 * REG];
#define SH(s)  ((ushort_t*)(smem + (s) * REG))
#define SVT(s) ((ushort_t*)(smem + (s) * REG))
#define SM(s)  ((ushort_t*)(smem + (s) * REG + MOFF))
#define SMF(s) ((float*)(smem + (s) * REG + MOFF))

    // ---- load h0 for both sequences -> s_h(s) (bf16) ----
#pragma unroll
    for (int s = 0; s < 2; s++) {
        const float4* px = (const float4*)(x + (size_t)(n0 + s) * 4096 + tid * 16);
        float h0[16];
#pragma unroll
        for (int q = 0; q < 4; q++) {
            float4 v = px[q];
            h0[4 * q] = v.x; h0[4 * q + 1] = v.y; h0[4 * q + 2] = v.z; h0[4 * q + 3] = v.w;
        }
        store16bf(SH(s) + l * 136 + ds, h0);
    }
    __syncthreads();                                   // B1

    // ================= QKV (shared weights, 2 chains per load) ===============
    {
        bf16x8 af[2][2][4];   // [s][mt][kk]
#pragma unroll
        for (int s = 0; s < 2; s++)
#pragma unroll
            for (int mt = 0; mt < 2; mt++)
#pragma unroll
                for (int kk = 0; kk < 4; kk++)
                    af[s][mt][kk] = *(const bf16x8*)(SH(s) + (mt * 16 + lh) * 136 + kk * 32 + lg * 8);
        __syncthreads();                               // B2: s_h dead; V^T may write region0

        const int ntb = wave * 6;
        float biasv[6];
#pragma unroll
        for (int j = 0; j < 6; j++) biasv[j] = b_qkv[(ntb + j) * 16 + lh];
#pragma unroll
        for (int j = 0; j < 6; j++) {
            bf16x8 bw[4];
#pragma unroll
            for (int kk = 0; kk < 4; kk++)
                bw[kk] = *(const bf16x8*)(wq_bf + (size_t)((ntb + j) * 16 + lh) * 128 + kk * 32 + lg * 8);
            f32x4 A[2][2];
#pragma unroll
            for (int s = 0; s < 2; s++) { A[s][0] = f32x4{0.f,0.f,0.f,0.f}; A[s][1] = f32x4{0.f,0.f,0.f,0.f}; }
            PRIO_HI();
#pragma unroll
            for (int kk = 0; kk < 4; kk++) {
#pragma unroll
                for (int s = 0; s < 2; s++) {
                    A[s][0] = MFMA(af[s][0][kk], bw[kk], A[s][0]);
                    A[s][1] = MFMA(af[s][1][kk], bw[kk], A[s][1]);
                }
            }
            PRIO_LO();
            const int nt  = ntb + j;
            const int col = nt * 16 + lh;
            const float bias = biasv[j];
#pragma unroll
            for (int s = 0; s < 2; s++) {
                if (nt < 16) {          // Q (cols 0-127) | K (cols 128-255)
                    const int r0 = lg * 4;
#pragma unroll
                    for (int i = 0; i < 4; i++) {
                        SM(s)[(r0 + i) * 260 + col]      = f2bf_hw(A[s][0][i] + bias);
                        SM(s)[(16 + r0 + i) * 260 + col] = f2bf_hw(A[s][1][i] + bias);
                    }
                } else {                // V -> transposed s_vt[dh][key] (region0)
                    const int vc = col - 256;
                    uint32 p01 = cvtpk(A[s][0][0] + bias, A[s][0][1] + bias);
                    uint32 p23 = cvtpk(A[s][0][2] + bias, A[s][0][3] + bias);
                    uint32 q01 = cvtpk(A[s][1][0] + bias, A[s][1][1] + bias);
                    uint32 q23 = cvtpk(A[s][1][2] + bias, A[s][1][3] + bias);
                    *(uint32*)&SVT(s)[vc * 36 + lg * 4]          = p01;
                    *(uint32*)&SVT(s)[vc * 36 + lg * 4 + 2]      = p23;
                    *(uint32*)&SVT(s)[vc * 36 + 16 + lg * 4]     = q01;
                    *(uint32*)&SVT(s)[vc * 36 + 16 + lg * 4 + 2] = q23;
                }
            }
        }
    }
    __syncthreads();                                   // B3: Q,K,V^T visible (both s)

    // ============ attention: BARRIER-FREE per-wave striped section ===========
    {
        // W_out weights + biases loaded ONCE, early (consumed after B6)
        bf16x8 wbo[2][4];
#pragma unroll
        for (int j = 0; j < 2; j++)
#pragma unroll
            for (int kk = 0; kk < 4; kk++)
                wbo[j][kk] = *(const bf16x8*)(wo_bf + (size_t)((wave * 2 + j) * 16 + lh) * 128 + kk * 32 + lg * 8);
        float bo0 = b_out[(wave * 2 + 0) * 16 + lh];
        float bo1 = b_out[(wave * 2 + 1) * 16 + lh];

#pragma unroll
        for (int s = 0; s < 2; s++) {
            // ---- QK^T both heads (must precede P: P(hd0) overwrites Q(hd1)) --
            f32x4 sA[2][2][2];   // [hd][mt][nt]
            bf16x8 bz = {};
            PRIO_HI();
#pragma unroll
            for (int hd = 0; hd < 2; hd++) {
                const int h8 = wave * 2 + hd;
#pragma unroll
                for (int mt = 0; mt < 2; mt++) {
                    bf16x8 aq = *(const bf16x8*)(SM(s) + (mt * 16 + lh) * 260 + h8 * 16 + (lg & 1) * 8);
#pragma unroll
                    for (int nt = 0; nt < 2; nt++) {
                        bf16x8 bk = bz;
                        if (lg < 2)
                            bk = *(const bf16x8*)(SM(s) + (nt * 16 + lh) * 260 + 128 + h8 * 16 + lg * 8);
                        f32x4 z = {0.f,0.f,0.f,0.f};
                        sA[hd][mt][nt] = MFMA(aq, bk, z);
                    }
                }
            }
            PRIO_LO();
            // ---- softmax + P into own stripes (wave-local) ----
#pragma unroll
            for (int hd = 0; hd < 2; hd++) {
                const int cb = hd ? (128 + wave * 32) : (wave * 32);
#pragma unroll
                for (int mt = 0; mt < 2; mt++) {
#pragma unroll
                    for (int i = 0; i < 4; i++) {
                        float e0 = __expf(sA[hd][mt][0][i] * 0.25f);
                        float e1 = __expf(sA[hd][mt][1][i] * 0.25f);
                        float sm = e0 + e1;
                        sm += __shfl_xor(sm, 1); sm += __shfl_xor(sm, 2);
                        sm += __shfl_xor(sm, 4); sm += __shfl_xor(sm, 8);
                        float inv = 1.0f / sm;
                        const int row = mt * 16 + lg * 4 + i;
                        SM(s)[row * 260 + cb + lh]      = f2bf_hw(e0 * inv);
                        SM(s)[row * 260 + cb + 16 + lh] = f2bf_hw(e1 * inv);
                    }
                }
            }
            // ---- PV -> O into own col stripe (wave-local) ----
            PRIO_HI();
#pragma unroll
            for (int hd = 0; hd < 2; hd++) {
                const int h8 = wave * 2 + hd;
                const int cb = hd ? (128 + wave * 32) : (wave * 32);
                bf16x8 bv = *(const bf16x8*)(SVT(s) + (h8 * 16 + lh) * 36 + lg * 8);
#pragma unroll
                for (int mt = 0; mt < 2; mt++) {
                    bf16x8 ap = *(const bf16x8*)(SM(s) + (mt * 16 + lh) * 260 + cb + lg * 8);
                    f32x4 z = {0.f,0.f,0.f,0.f};
                    f32x4 o = MFMA(ap, bv, z);
                    const int r0 = mt * 16 + lg * 4, c = h8 * 16 + lh;
#pragma unroll
                    for (int i = 0; i < 4; i++)
                        SM(s)[(r0 + i) * 260 + c] = f2bf_hw(o[i]);
                }
            }
            PRIO_LO();
        }
        __syncthreads();                               // B6: O complete (both s)
        // W_out -> u (bf16, region0(s)); shared wbo, 2 chains
#pragma unroll
        for (int s = 0; s < 2; s++) {
            bf16x8 af2[2][4];
#pragma unroll
            for (int mt = 0; mt < 2; mt++)
#pragma unroll
                for (int kk = 0; kk < 4; kk++)
                    af2[mt][kk] = *(const bf16x8*)(SM(s) + (mt * 16 + lh) * 260 + kk * 32 + lg * 8);
#pragma unroll
            for (int j = 0; j < 2; j++) {
                f32x4 a0 = {0.f,0.f,0.f,0.f}, a1 = {0.f,0.f,0.f,0.f};
                PRIO_HI();
#pragma unroll
                for (int kk = 0; kk < 4; kk++) {
                    a0 = MFMA(af2[0][kk], wbo[j][kk], a0);
                    a1 = MFMA(af2[1][kk], wbo[j][kk], a1);
                }
                PRIO_LO();
                const int col = (wave * 2 + j) * 16 + lh;
                const float bias = j ? bo1 : bo0;
#pragma unroll
                for (int i = 0; i < 4; i++) {
                    SH(s)[(lg * 4 + i) * 136 + col]      = f2bf_hw(a0[i] + bias);
                    SH(s)[(16 + lg * 4 + i) * 136 + col] = f2bf_hw(a1[i] + bias);
                }
            }
        }
        __syncthreads();                               // B7: u visible (both s)
        // LN1: h1 = LN(h0 + u) -> s_h(s), both s (gamma/beta loaded once)
        {
            float g[16], be[16];
            {
                const float4* pg = (const float4*)(ln1g + ds);
                const float4* pb = (const float4*)(ln1b + ds);
#pragma unroll
                for (int q = 0; q < 4; q++) {
                    float4 vg = pg[q], vb = pb[q];
                    g[4*q]=vg.x; g[4*q+1]=vg.y; g[4*q+2]=vg.z; g[4*q+3]=vg.w;
                    be[4*q]=vb.x; be[4*q+1]=vb.y; be[4*q+2]=vb.z; be[4*q+3]=vb.w;
                }
            }
#pragma unroll
            for (int s = 0; s < 2; s++) {
                const float4* px = (const float4*)(x + (size_t)(n0 + s) * 4096 + tid * 16);
                float4 hx0 = px[0], hx1 = px[1], hx2 = px[2], hx3 = px[3];
                float h0v[16];
                { float4 v = hx0; h0v[0]=v.x; h0v[1]=v.y; h0v[2]=v.z; h0v[3]=v.w; }
                { float4 v = hx1; h0v[4]=v.x; h0v[5]=v.y; h0v[6]=v.z; h0v[7]=v.w; }
                { float4 v = hx2; h0v[8]=v.x; h0v[9]=v.y; h0v[10]=v.z; h0v[11]=v.w; }
                { float4 v = hx3; h0v[12]=v.x; h0v[13]=v.y; h0v[14]=v.z; h0v[15]=v.w; }
                float t[16]; float sum = 0.f;
#pragma unroll
                for (int i = 0; i < 16; i++) {
                    t[i] = h0v[i] + bf2f((uint32)SH(s)[l * 136 + ds + i]);
                    sum += t[i];
                }
                sum += __shfl_xor(sum, 1); sum += __shfl_xor(sum, 2); sum += __shfl_xor(sum, 4);
                float mean = sum * (1.f / 128.f);
                float vs = 0.f;
#pragma unroll
                for (int i = 0; i < 16; i++) { float d = t[i] - mean; vs += d * d; }
                vs += __shfl_xor(vs, 1); vs += __shfl_xor(vs, 2); vs += __shfl_xor(vs, 4);
                float rs = rsqrtf(vs * (1.f / 128.f) + 1e-5f);
                float h1v[16];
#pragma unroll
                for (int i = 0; i < 16; i++)
                    h1v[i] = (t[i] - mean) * rs * g[i] + be[i];
                store16bf(SH(s) + l * 136 + ds, h1v);  // own addrs
            }
        }
    }
    __syncthreads();                                   // B8: h1 visible (both s)

    // ================= FFN (two K=256 rounds; FFN2 shares weights) ===========
    f32x4 fa[2][4];   // [s][{00,01,10,11}]
#pragma unroll
    for (int s = 0; s < 2; s++)
#pragma unroll
        for (int q = 0; q < 4; q++) fa[s][q] = f32x4{0.f,0.f,0.f,0.f};
    const int col0 = wave * 32 + lh, col1 = col0 + 16;
#pragma unroll
    for (int r = 0; r < 2; r++) {
        // ---- FFN1 per s: 4 column-tiles per wave -> s_m(s) ----
#pragma unroll
        for (int s = 0; s < 2; s++) {
            bf16x8 ah[2][4];
#pragma unroll
            for (int mt = 0; mt < 2; mt++)
#pragma unroll
                for (int kk = 0; kk < 4; kk++)
                    ah[mt][kk] = *(const bf16x8*)(SH(s) + (mt * 16 + lh) * 136 + kk * 32 + lg * 8);
            float b1v[4];
#pragma unroll
            for (int j = 0; j < 4; j++) b1v[j] = b1[(r * 16 + wave * 4 + j) * 16 + lh];
#pragma unroll
            for (int j = 0; j < 4; j++) {
                bf16x8 bw[4];
                {
                    const int nt = (r * 16 + wave * 4 + j) * 16 + lh;
#pragma unroll
                    for (int kk = 0; kk < 4; kk++)
                        bw[kk] = *(const bf16x8*)(w1_bf + (size_t)nt * 128 + kk * 32 + lg * 8);
                }
                f32x4 a0 = {0.f,0.f,0.f,0.f}, a1 = {0.f,0.f,0.f,0.f};
                PRIO_HI();
#pragma unroll
                for (int kk = 0; kk < 4; kk++) {
                    a0 = MFMA(ah[0][kk], bw[kk], a0);
                    a1 = MFMA(ah[1][kk], bw[kk], a1);
                }
                PRIO_LO();
                const float bias = b1v[j];
                const int cl = (wave * 4 + j) * 16 + lh;
                const int r0 = lg * 4;
#pragma unroll
                for (int i = 0; i < 4; i++) {
                    SM(s)[(r0 + i) * 260 + cl]      = f2bf_hw(fmaxf(a0[i] + bias, 0.f));
                    SM(s)[(16 + r0 + i) * 260 + cl] = f2bf_hw(fmaxf(a1[i] + bias, 0.f));
                }
            }
        }
        __syncthreads();                               // B9(r): f1 visible (both s)
        // ---- FFN2: shared w2 slices, 2 chains per load ----
#pragma unroll
        for (int kk = 0; kk < 8; kk++) {
            bf16x8 wp0 = *(const bf16x8*)(w2_bf + (size_t)col0 * 512 + r * 256 + kk * 32 + lg * 8);
            bf16x8 wp1 = *(const bf16x8*)(w2_bf + (size_t)col1 * 512 + r * 256 + kk * 32 + lg * 8);
            PRIO_HI();
#pragma unroll
            for (int s = 0; s < 2; s++) {
                bf16x8 a0 = *(const bf16x8*)(SM(s) + lh * 260 + kk * 32 + lg * 8);
                bf16x8 a1 = *(const bf16x8*)(SM(s) + (16 + lh) * 260 + kk * 32 + lg * 8);
                fa[s][0] = MFMA(a0, wp0, fa[s][0]);
                fa[s][1] = MFMA(a1, wp0, fa[s][1]);
                fa[s][2] = MFMA(a0, wp1, fa[s][2]);
                fa[s][3] = MFMA(a1, wp1, fa[s][3]);
            }
            PRIO_LO();
        }
        __syncthreads();                               // B10(r): f1 reads done
    }
    // ---- f2 -> s_mf(s) (fp32, stride 130) ----
    {
        const float bi0 = b2[col0], bi1 = b2[col1];
#pragma unroll
        for (int s = 0; s < 2; s++) {
#pragma unroll
            for (int i = 0; i < 4; i++) {
                SMF(s)[(lg * 4 + i) * 130 + col0]      = fa[s][0][i] + bi0;
                SMF(s)[(16 + lg * 4 + i) * 130 + col0] = fa[s][1][i] + bi0;
                SMF(s)[(lg * 4 + i) * 130 + col1]      = fa[s][2][i] + bi1;
                SMF(s)[(16 + lg * 4 + i) * 130 + col1] = fa[s][3][i] + bi1;
            }
        }
    }
    __syncthreads();                                   // B11: f2 visible

    // ================= LN2 + out + h2 -> s_h(s), per s =======================
    {
        float g[16], be[16];
        {
            const float4* pg = (const float4*)(ln2g + ds);
            const float4* pb = (const float4*)(ln2b + ds);
#pragma unroll
            for (int q = 0; q < 4; q++) {
                float4 vg = pg[q], vb = pb[q];
                g[4*q]=vg.x; g[4*q+1]=vg.y; g[4*q+2]=vg.z; g[4*q+3]=vg.w;
                be[4*q]=vb.x; be[4*q+1]=vb.y; be[4*q+2]=vb.z; be[4*q+3]=vb.w;
            }
        }
#pragma unroll
        for (int s = 0; s < 2; s++) {
            float t[16]; float sum = 0.f;
#pragma unroll
            for (int i = 0; i < 16; i++) {
                t[i] = bf2f((uint32)SH(s)[l * 136 + ds + i]) + SMF(s)[l * 130 + ds + i];
                sum += t[i];
            }
            sum += __shfl_xor(sum, 1); sum += __shfl_xor(sum, 2); sum += __shfl_xor(sum, 4);
            float mean = sum * (1.f / 128.f);
            float vs = 0.f;
#pragma unroll
            for (int i = 0; i < 16; i++) { float d = t[i] - mean; vs += d * d; }
            vs += __shfl_xor(vs, 1); vs += __shfl_xor(vs, 2); vs += __shfl_xor(vs, 4);
            float rs = rsqrtf(vs * (1.f / 128.f) + 1e-5f);
            float h2v[16];
#pragma unroll
            for (int i = 0; i < 16; i++)
                h2v[i] = (t[i] - mean) * rs * g[i] + be[i];
            float4* po = (float4*)(out_xt + (size_t)(n0 + s) * 4096 + tid * 16);
#pragma unroll
            for (int q = 0; q < 4; q++)
                po[q] = make_float4(h2v[4 * q], h2v[4 * q + 1], h2v[4 * q + 2], h2v[4 * q + 3]);
            store16bf(SH(s) + l * 136 + ds, h2v);      // own addrs
        }
    }
    __syncthreads();                                   // B12: h2 visible

    // ================= GCN weight GEMM (shared weights) ======================
    {
        bf16x8 wb[2][4];
#pragma unroll
        for (int j = 0; j < 2; j++)
#pragma unroll
            for (int kk = 0; kk < 4; kk++)
                wb[j][kk] = *(const bf16x8*)(wg_bf + (size_t)((wave * 2 + j) * 16 + lh) * 128 + kk * 32 + lg * 8);
#pragma unroll
        for (int s = 0; s < 2; s++) {
            bf16x8 ag[2][4];
#pragma unroll
            for (int mt = 0; mt < 2; mt++)
#pragma unroll
                for (int kk = 0; kk < 4; kk++)
                    ag[mt][kk] = *(const bf16x8*)(SH(s) + (mt * 16 + lh) * 136 + kk * 32 + lg * 8);
            ushort_t* hp = hh + (size_t)(n0 + s) * 4096;
#pragma unroll
            for (int j = 0; j < 2; j++) {
                f32x4 a0 = {0.f,0.f,0.f,0.f}, a1 = {0.f,0.f,0.f,0.f};
                PRIO_HI();
#pragma unroll
                for (int kk = 0; kk < 4; kk++) {
                    a0 = MFMA(ag[0][kk], wb[j][kk], a0);
                    a1 = MFMA(ag[1][kk], wb[j][kk], a1);
                }
                PRIO_LO();
                const int col = (wave * 2 + j) * 16 + lh;
                const int r0 = lg * 4;
#pragma unroll
                for (int i = 0; i < 4; i++) {
                    hp[(r0 + i) * 128 + col]      = f2bf_hw(a0[i]);
                    hp[(16 + r0 + i) * 128 + col] = f2bf_hw(a1[i]);
                }
            }
        }
    }
#undef SH
#undef SVT
#undef SM
#undef SMF
}

// ---------------------------------------------------------------------------
// GCN support kernels
// ---------------------------------------------------------------------------
__global__ void k_degcount(const int* __restrict__ ei, const float* __restrict__ ew,
                           float* deg, int* count) {
    int idx = blockIdx.x * 256 + threadIdx.x;
    if (idx >= BDIM * EDIM) return;
    int b = idx / EDIM, e = idx - b * EDIM;
    int col = ei[(size_t)b * 2 * EDIM + EDIM + e];
    float w = ew[(size_t)b * EDIM + e];
    atomicAdd(&deg[b * KDIM + col], w);
    atomicAdd(&count[b * KDIM + col], 1);
}

__global__ __launch_bounds__(1024)
void k_scan(const int* __restrict__ count, int* offs, int* cursor) {
    __shared__ int s[KDIM];
    int b = blockIdx.x, i = threadIdx.x;
    int c = count[b * KDIM + i];
    s[i] = c; __syncthreads();
#pragma unroll 1
    for (int off = 1; off < KDIM; off <<= 1) {
        int t = (i >= off) ? s[i - off] : 0;
        __syncthreads();
        s[i] += t;
        __syncthreads();
    }
    int excl = s[i] - c;
    offs[b * KDIM + i] = excl;
    cursor[b * KDIM + i] = excl;
}

__global__ void k_fill(const int* __restrict__ ei, int* cursor, int* elist) {
    int idx = blockIdx.x * 256 + threadIdx.x;
    if (idx >= BDIM * EDIM) return;
    int b = idx / EDIM, e = idx - b * EDIM;
    int col = ei[(size_t)b * 2 * EDIM + EDIM + e];
    int pos = atomicAdd(&cursor[b * KDIM + col], 1);
    elist[(size_t)b * EDIM + pos] = e;
}

// One block per node (XCD-swizzled: each XCD gets a contiguous 512-node range
// of a single batch -> per-XCD L2 working set 8 MB instead of 33 MB).
// DUAL-CHAIN edge loop: 2 rows in flight, next pair's indices prefetched.
__global__ __launch_bounds__(256)
void k_gather(const int* __restrict__ ei, const float* __restrict__ ew,
              const float* __restrict__ deg, const int* __restrict__ offs,
              const int* __restrict__ count, const int* __restrict__ elist,
              const ushort_t* __restrict__ hh, const float* __restrict__ gcn_b,
              float* __restrict__ out)
{
    const int bid  = blockIdx.x;
    const int node = (bid & 7) * (NSEQ / 8) + (bid >> 3);   // bijective XCD swizzle
    const int b = node >> 10, i = node & 1023;
    const int tid = threadIdx.x;
    const float dcol = rsqrtf(deg[node]);
    const int off = offs[node], cnt = count[node];
    const ushort_t* hhb = hh + ((size_t)b * KDIM) * 4096;
    const int* elb = elist + (size_t)b * EDIM;
    const int* eib = ei + (size_t)b * 2 * EDIM;
    const float* ewb = ew + (size_t)b * EDIM;
    const float* degb = deg + b * KDIM;

    float acc[16];
    {
        const uint4* ph = (const uint4*)(hhb + (size_t)i * 4096 + tid * 16);
        uint4 a = ph[0], bb = ph[1];
        float tmp[16]; unpack8(a, tmp); unpack8(bb, tmp + 8);
        float nrm = dcol * dcol;
#pragma unroll
        for (int k = 0; k < 16; k++) acc[k] = tmp[k] * nrm;
    }
    if (cnt > 0) {
        int rowA, rowB = 0; float wA, wB = 0.f;
        {
            int eA = elb[off];
            rowA = eib[eA]; wA = ewb[eA];
            if (cnt > 1) { int eB = elb[off + 1]; rowB = eib[eB]; wB = ewb[eB]; }
        }
        for (int t = 0; t < cnt; t += 2) {
            const bool hasB = (t + 1 < cnt);
            const uint4* pA = (const uint4*)(hhb + (size_t)rowA * 4096 + tid * 16);
            uint4 a0 = pA[0], a1 = pA[1];
            uint4 b0 = make_uint4(0, 0, 0, 0), b1 = make_uint4(0, 0, 0, 0);
            if (hasB) {
                const uint4* pB = (const uint4*)(hhb + (size_t)rowB * 4096 + tid * 16);
                b0 = pB[0]; b1 = pB[1];
            }
            float nA = rsqrtf(degb[rowA]) * wA * dcol;
            float nB = hasB ? rsqrtf(degb[rowB]) * wB * dcol : 0.f;
            int rA2 = 0, rB2 = 0; float wA2 = 0.f, wB2 = 0.f;
            if (t + 2 < cnt) { int e = elb[off + t + 2]; rA2 = eib[e]; wA2 = ewb[e]; }
            if (t + 3 < cnt) { int e = elb[off + t + 3]; rB2 = eib[e]; wB2 = ewb[e]; }
            float tA[16]; unpack8(a0, tA); unpack8(a1, tA + 8);
#pragma unroll
            for (int k = 0; k < 16; k++) acc[k] += tA[k] * nA;
            float tB[16]; unpack8(b0, tB); unpack8(b1, tB + 8);
#pragma unroll
            for (int k = 0; k < 16; k++) acc[k] += tB[k] * nB;
            rowA = rA2; wA = wA2; rowB = rB2; wB = wB2;
        }
    }
    const int d0 = (tid * 16) & 127;
    float4* po = (float4*)(out + (size_t)node * 4096 + tid * 16);
#pragma unroll
    for (int q = 0; q < 4; q++) {
        float4 xo = po[q];
        xo.x += acc[4 * q]     + gcn_b[d0 + 4 * q];
        xo.y += acc[4 * q + 1] + gcn_b[d0 + 4 * q + 1];
        xo.z += acc[4 * q + 2] + gcn_b[d0 + 4 * q + 2];
        xo.w += acc[4 * q + 3] + gcn_b[d0 + 4 * q + 3];
        po[q] = xo;
    }
}

// ---------------------------------------------------------------------------
extern "C" void kernel_launch(void* const* d_in, const int* in_sizes, int n_in,
                              void* d_out, int out_size, void* d_ws, size_t ws_size,
                              hipStream_t stream) {
    const float* x     = (const float*)d_in[0];
    const int*   ei    = (const int*)d_in[1];
    const float* ew    = (const float*)d_in[2];
    const float* w_qkv = (const float*)d_in[3];
    const float* b_qkv = (const float*)d_in[4];
    const float* w_out = (const float*)d_in[5];
    const float* b_out = (const float*)d_in[6];
    const float* w1    = (const float*)d_in[7];
    const float* b1    = (const float*)d_in[8];
    const float* w2    = (const float*)d_in[9];
    const float* b2    = (const float*)d_in[10];
    const float* ln1g  = (const float*)d_in[11];
    const float* ln1b  = (const float*)d_in[12];
    const float* ln2g  = (const float*)d_in[13];
    const float* ln2b  = (const float*)d_in[14];
    const float* gcnw  = (const float*)d_in[15];
    const float* gcnb  = (const float*)d_in[16];
    float* out = (float*)d_out;

    // ws layout (bytes): weights 425984 | deg/count/offs/cursor 4x16384 | elist 262144 | hh 33554432
    char* ws = (char*)d_ws;
    ushort_t* wbf   = (ushort_t*)ws;
    ushort_t* wq_bf = wbf;
    ushort_t* wo_bf = wbf + 49152;
    ushort_t* w1_bf = wbf + 65536;
    ushort_t* w2_bf = wbf + 131072;
    ushort_t* wg_bf = wbf + 196608;
    float*    deg   = (float*)(ws + 425984);
    int*      count = (int*)(ws + 442368);
    int*      offs  = (int*)(ws + 458752);
    int*      cursor= (int*)(ws + 475136);
    int*      elist = (int*)(ws + 491520);
    ushort_t* hh    = (ushort_t*)(ws + 753664);

    k_prep<<<(NWCVT + 255) / 256, 256, 0, stream>>>(w_qkv, w_out, w1, w2, gcnw, wbf, deg, count);
    k_transformer<<<NSEQ / 2, 256, 0, stream>>>(x, wq_bf, b_qkv, wo_bf, b_out,
                                                w1_bf, b1, w2_bf, b2, wg_bf,
                                                ln1g, ln1b, ln2g, ln2b, out, hh);
    k_degcount<<<256, 256, 0, stream>>>(ei, ew, deg, count);
    k_scan<<<BDIM, 1024, 0, stream>>>(count, offs, cursor);
    k_fill<<<256, 256, 0, stream>>>(ei, cursor, elist);
    k_gather<<<NSEQ, 256, 0, stream>>>(ei, ew, deg, offs, count, elist, hh, gcnb, out);
}

// Round 22
// 273.185 us; speedup vs baseline: 1.1368x; 1.0095x over previous
//
#include <hip/hip_runtime.h>
#include <hip/hip_bf16.h>

// Problem constants
#define BDIM 4
#define KDIM 1024
#define EDIM 16384
#define NSEQ (BDIM * KDIM)   // 4096
#define REG  25856           // per-sequence LDS region stride (bytes)
#define MOFF 9216            // s_m offset within region (after s_vt [128][36])

typedef unsigned short ushort_t;
typedef unsigned int   uint32;

typedef __bf16 bf16x8 __attribute__((ext_vector_type(8)));
typedef float  f32x4  __attribute__((ext_vector_type(4)));

#define MFMA(A, B, C) __builtin_amdgcn_mfma_f32_16x16x32_bf16((A), (B), (C), 0, 0, 0)
#define PRIO_HI() __builtin_amdgcn_s_setprio(1)
#define PRIO_LO() __builtin_amdgcn_s_setprio(0)

__device__ __forceinline__ float bf2f(uint32 u) {
    union { uint32 i; float f; } v; v.i = u << 16; return v.f;
}
__device__ __forceinline__ ushort_t f2bf(float f) {
    union { float f; uint32 i; } v; v.f = f;
    uint32 r = (v.i + 0x7fffu + ((v.i >> 16) & 1u)) >> 16;
    return (ushort_t)r;
}
// hardware packed cvt: {lo=bf16(a), hi=bf16(b)}, RNE
__device__ __forceinline__ uint32 cvtpk(float a, float b) {
    uint32 r;
    asm("v_cvt_pk_bf16_f32 %0, %1, %2" : "=v"(r) : "v"(a), "v"(b));
    return r;
}
__device__ __forceinline__ ushort_t f2bf_hw(float f) { return (ushort_t)cvtpk(f, f); }

__device__ __forceinline__ void unpack8(uint4 v, float* dst) {
    const uint32* pv = (const uint32*)&v;
#pragma unroll
    for (int q = 0; q < 4; q++) {
        uint32 w = pv[q];
        dst[2 * q]     = bf2f(w & 0xffffu);
        dst[2 * q + 1] = bf2f(w >> 16);
    }
}
// pack 16 floats -> 16 bf16 (32B) at p (16B-aligned)
__device__ __forceinline__ void store16bf(ushort_t* p, const float* v) {
    uint32 w[8];
#pragma unroll
    for (int q = 0; q < 8; q++) w[q] = cvtpk(v[2 * q], v[2 * q + 1]);
    ((uint4*)p)[0] = make_uint4(w[0], w[1], w[2], w[3]);
    ((uint4*)p)[1] = make_uint4(w[4], w[5], w[6], w[7]);
}

// ---------------------------------------------------------------------------
// Weight pre-conversion fp32 -> bf16 into ws (+ fused deg/count init):
//   wqkv [384][128] @0 | wout [128][128] @49152 | w1 [512][128] @65536
//   w2 [128][512] @131072 | gcnw [128][128] @196608   (elements)
// ---------------------------------------------------------------------------
#define NWCVT 212992
__global__ void k_prep(const float* __restrict__ wq, const float* __restrict__ wo,
                       const float* __restrict__ w1, const float* __restrict__ w2,
                       const float* __restrict__ wg, ushort_t* __restrict__ dst,
                       float* __restrict__ deg, int* __restrict__ count) {
    int i = blockIdx.x * 256 + threadIdx.x;
    if (i >= NWCVT) return;
    if (i < BDIM * KDIM) { deg[i] = 1.0f; count[i] = 0; }   // fused k_init
    float v;
    if      (i <  49152) v = wq[i];
    else if (i <  65536) v = wo[i - 49152];
    else if (i < 131072) v = w1[i - 65536];
    else if (i < 196608) v = w2[i - 131072];
    else                 v = wg[i - 196608];
    dst[i] = f2bf(v);
}

// ---------------------------------------------------------------------------
// Fused transformer layer (session optimum): 2 seq/block, shared-weight
// QKV/W_out/FFN2/GCN, barrier-free striped attention, 12 barriers/block,
// T5 s_setprio around MFMA clusters (VGPR 84 -> 3 blocks/CU), PLUS fused
// degcount: 32 edge-atomics per block issued at kernel start, draining
// under the 200+ us of MFMA work (replaces the k_degcount launch).
// NO launch_bounds min-waves (pinned miscompile r7/r8).
// LDS 2 x 25856 = 51712 B.
// Region: s_h[32][136]<alias>s_vt[128][36] @0; s_m[32][260]|s_mf[32][130] @9216.
// ---------------------------------------------------------------------------
__global__ __launch_bounds__(256)
void k_transformer(const float* __restrict__ x,
                   const ushort_t* __restrict__ wq_bf, const float* __restrict__ b_qkv,
                   const ushort_t* __restrict__ wo_bf, const float* __restrict__ b_out,
                   const ushort_t* __restrict__ w1_bf, const float* __restrict__ b1,
                   const ushort_t* __restrict__ w2_bf, const float* __restrict__ b2,
                   const ushort_t* __restrict__ wg_bf,
                   const float* __restrict__ ln1g, const float* __restrict__ ln1b,
                   const float* __restrict__ ln2g, const float* __restrict__ ln2b,
                   const int* __restrict__ ei, const float* __restrict__ ew,
                   float* __restrict__ deg, int* __restrict__ count,
                   float* __restrict__ out_xt, ushort_t* __restrict__ hh)
{
    const int n0   = blockIdx.x * 2;
    const int tid  = threadIdx.x;
    const int wave = tid >> 6;
    const int lane = tid & 63;
    const int lh   = lane & 15;      // M-row / N-col within 16x16 tile
    const int lg   = lane >> 4;      // k-group (8 elems each)
    const int l    = tid >> 3;       // per-thread row (LN phases)
    const int ds   = (tid & 7) * 16;

    // ---- fused degcount: 32 edges/block, atomics drain under MFMA work ----
    if (tid < 32) {
        const int idx = blockIdx.x * 32 + tid;      // 2048*32 = 65536 = B*E
        const int eb  = idx >> 14;                  // / EDIM
        const int e   = idx & (EDIM - 1);
        const int col = ei[(size_t)eb * 2 * EDIM + EDIM + e];
        atomicAdd(&deg[eb * KDIM + col], ew[(size_t)eb * EDIM + e]);
        atomicAdd(&count[eb * KDIM + col], 1);
    }

    __shared__ __align__(16) char smem[2 * REG];
#define SH(s)  ((ushort_t*)(smem + (s) * REG))
#define SVT(s) ((ushort_t*)(smem + (s) * REG))
#define SM(s)  ((ushort_t*)(smem + (s) * REG + MOFF))
#define SMF(s) ((float*)(smem + (s) * REG + MOFF))

    // ---- load h0 for both sequences -> s_h(s) (bf16) ----
#pragma unroll
    for (int s = 0; s < 2; s++) {
        const float4* px = (const float4*)(x + (size_t)(n0 + s) * 4096 + tid * 16);
        float h0[16];
#pragma unroll
        for (int q = 0; q < 4; q++) {
            float4 v = px[q];
            h0[4 * q] = v.x; h0[4 * q + 1] = v.y; h0[4 * q + 2] = v.z; h0[4 * q + 3] = v.w;
        }
        store16bf(SH(s) + l * 136 + ds, h0);
    }
    __syncthreads();                                   // B1

    // ================= QKV (shared weights, 2 chains per load) ===============
    {
        bf16x8 af[2][2][4];   // [s][mt][kk]
#pragma unroll
        for (int s = 0; s < 2; s++)
#pragma unroll
            for (int mt = 0; mt < 2; mt++)
#pragma unroll
                for (int kk = 0; kk < 4; kk++)
                    af[s][mt][kk] = *(const bf16x8*)(SH(s) + (mt * 16 + lh) * 136 + kk * 32 + lg * 8);
        __syncthreads();                               // B2: s_h dead; V^T may write region0

        const int ntb = wave * 6;
        float biasv[6];
#pragma unroll
        for (int j = 0; j < 6; j++) biasv[j] = b_qkv[(ntb + j) * 16 + lh];
#pragma unroll
        for (int j = 0; j < 6; j++) {
            bf16x8 bw[4];
#pragma unroll
            for (int kk = 0; kk < 4; kk++)
                bw[kk] = *(const bf16x8*)(wq_bf + (size_t)((ntb + j) * 16 + lh) * 128 + kk * 32 + lg * 8);
            f32x4 A[2][2];
#pragma unroll
            for (int s = 0; s < 2; s++) { A[s][0] = f32x4{0.f,0.f,0.f,0.f}; A[s][1] = f32x4{0.f,0.f,0.f,0.f}; }
            PRIO_HI();
#pragma unroll
            for (int kk = 0; kk < 4; kk++) {
#pragma unroll
                for (int s = 0; s < 2; s++) {
                    A[s][0] = MFMA(af[s][0][kk], bw[kk], A[s][0]);
                    A[s][1] = MFMA(af[s][1][kk], bw[kk], A[s][1]);
                }
            }
            PRIO_LO();
            const int nt  = ntb + j;
            const int col = nt * 16 + lh;
            const float bias = biasv[j];
#pragma unroll
            for (int s = 0; s < 2; s++) {
                if (nt < 16) {          // Q (cols 0-127) | K (cols 128-255)
                    const int r0 = lg * 4;
#pragma unroll
                    for (int i = 0; i < 4; i++) {
                        SM(s)[(r0 + i) * 260 + col]      = f2bf_hw(A[s][0][i] + bias);
                        SM(s)[(16 + r0 + i) * 260 + col] = f2bf_hw(A[s][1][i] + bias);
                    }
                } else {                // V -> transposed s_vt[dh][key] (region0)
                    const int vc = col - 256;
                    uint32 p01 = cvtpk(A[s][0][0] + bias, A[s][0][1] + bias);
                    uint32 p23 = cvtpk(A[s][0][2] + bias, A[s][0][3] + bias);
                    uint32 q01 = cvtpk(A[s][1][0] + bias, A[s][1][1] + bias);
                    uint32 q23 = cvtpk(A[s][1][2] + bias, A[s][1][3] + bias);
                    *(uint32*)&SVT(s)[vc * 36 + lg * 4]          = p01;
                    *(uint32*)&SVT(s)[vc * 36 + lg * 4 + 2]      = p23;
                    *(uint32*)&SVT(s)[vc * 36 + 16 + lg * 4]     = q01;
                    *(uint32*)&SVT(s)[vc * 36 + 16 + lg * 4 + 2] = q23;
                }
            }
        }
    }
    __syncthreads();                                   // B3: Q,K,V^T visible (both s)

    // ============ attention: BARRIER-FREE per-wave striped section ===========
    {
        // W_out weights + biases loaded ONCE, early (consumed after B6)
        bf16x8 wbo[2][4];
#pragma unroll
        for (int j = 0; j < 2; j++)
#pragma unroll
            for (int kk = 0; kk < 4; kk++)
                wbo[j][kk] = *(const bf16x8*)(wo_bf + (size_t)((wave * 2 + j) * 16 + lh) * 128 + kk * 32 + lg * 8);
        float bo0 = b_out[(wave * 2 + 0) * 16 + lh];
        float bo1 = b_out[(wave * 2 + 1) * 16 + lh];

#pragma unroll
        for (int s = 0; s < 2; s++) {
            // ---- QK^T both heads (must precede P: P(hd0) overwrites Q(hd1)) --
            f32x4 sA[2][2][2];   // [hd][mt][nt]
            bf16x8 bz = {};
            PRIO_HI();
#pragma unroll
            for (int hd = 0; hd < 2; hd++) {
                const int h8 = wave * 2 + hd;
#pragma unroll
                for (int mt = 0; mt < 2; mt++) {
                    bf16x8 aq = *(const bf16x8*)(SM(s) + (mt * 16 + lh) * 260 + h8 * 16 + (lg & 1) * 8);
#pragma unroll
                    for (int nt = 0; nt < 2; nt++) {
                        bf16x8 bk = bz;
                        if (lg < 2)
                            bk = *(const bf16x8*)(SM(s) + (nt * 16 + lh) * 260 + 128 + h8 * 16 + lg * 8);
                        f32x4 z = {0.f,0.f,0.f,0.f};
                        sA[hd][mt][nt] = MFMA(aq, bk, z);
                    }
                }
            }
            PRIO_LO();
            // ---- softmax + P into own stripes (wave-local) ----
#pragma unroll
            for (int hd = 0; hd < 2; hd++) {
                const int cb = hd ? (128 + wave * 32) : (wave * 32);
#pragma unroll
                for (int mt = 0; mt < 2; mt++) {
#pragma unroll
                    for (int i = 0; i < 4; i++) {
                        float e0 = __expf(sA[hd][mt][0][i] * 0.25f);
                        float e1 = __expf(sA[hd][mt][1][i] * 0.25f);
                        float sm = e0 + e1;
                        sm += __shfl_xor(sm, 1); sm += __shfl_xor(sm, 2);
                        sm += __shfl_xor(sm, 4); sm += __shfl_xor(sm, 8);
                        float inv = 1.0f / sm;
                        const int row = mt * 16 + lg * 4 + i;
                        SM(s)[row * 260 + cb + lh]      = f2bf_hw(e0 * inv);
                        SM(s)[row * 260 + cb + 16 + lh] = f2bf_hw(e1 * inv);
                    }
                }
            }
            // ---- PV -> O into own col stripe (wave-local) ----
            PRIO_HI();
#pragma unroll
            for (int hd = 0; hd < 2; hd++) {
                const int h8 = wave * 2 + hd;
                const int cb = hd ? (128 + wave * 32) : (wave * 32);
                bf16x8 bv = *(const bf16x8*)(SVT(s) + (h8 * 16 + lh) * 36 + lg * 8);
#pragma unroll
                for (int mt = 0; mt < 2; mt++) {
                    bf16x8 ap = *(const bf16x8*)(SM(s) + (mt * 16 + lh) * 260 + cb + lg * 8);
                    f32x4 z = {0.f,0.f,0.f,0.f};
                    f32x4 o = MFMA(ap, bv, z);
                    const int r0 = mt * 16 + lg * 4, c = h8 * 16 + lh;
#pragma unroll
                    for (int i = 0; i < 4; i++)
                        SM(s)[(r0 + i) * 260 + c] = f2bf_hw(o[i]);
                }
            }
            PRIO_LO();
        }
        __syncthreads();                               // B6: O complete (both s)
        // W_out -> u (bf16, region0(s)); shared wbo, 2 chains
#pragma unroll
        for (int s = 0; s < 2; s++) {
            bf16x8 af2[2][4];
#pragma unroll
            for (int mt = 0; mt < 2; mt++)
#pragma unroll
                for (int kk = 0; kk < 4; kk++)
                    af2[mt][kk] = *(const bf16x8*)(SM(s) + (mt * 16 + lh) * 260 + kk * 32 + lg * 8);
#pragma unroll
            for (int j = 0; j < 2; j++) {
                f32x4 a0 = {0.f,0.f,0.f,0.f}, a1 = {0.f,0.f,0.f,0.f};
                PRIO_HI();
#pragma unroll
                for (int kk = 0; kk < 4; kk++) {
                    a0 = MFMA(af2[0][kk], wbo[j][kk], a0);
                    a1 = MFMA(af2[1][kk], wbo[j][kk], a1);
                }
                PRIO_LO();
                const int col = (wave * 2 + j) * 16 + lh;
                const float bias = j ? bo1 : bo0;
#pragma unroll
                for (int i = 0; i < 4; i++) {
                    SH(s)[(lg * 4 + i) * 136 + col]      = f2bf_hw(a0[i] + bias);
                    SH(s)[(16 + lg * 4 + i) * 136 + col] = f2bf_hw(a1[i] + bias);
                }
            }
        }
        __syncthreads();                               // B7: u visible (both s)
        // LN1: h1 = LN(h0 + u) -> s_h(s), both s (gamma/beta loaded once)
        {
            float g[16], be[16];
            {
                const float4* pg = (const float4*)(ln1g + ds);
                const float4* pb = (const float4*)(ln1b + ds);
#pragma unroll
                for (int q = 0; q < 4; q++) {
                    float4 vg = pg[q], vb = pb[q];
                    g[4*q]=vg.x; g[4*q+1]=vg.y; g[4*q+2]=vg.z; g[4*q+3]=vg.w;
                    be[4*q]=vb.x; be[4*q+1]=vb.y; be[4*q+2]=vb.z; be[4*q+3]=vb.w;
                }
            }
#pragma unroll
            for (int s = 0; s < 2; s++) {
                const float4* px = (const float4*)(x + (size_t)(n0 + s) * 4096 + tid * 16);
                float4 hx0 = px[0], hx1 = px[1], hx2 = px[2], hx3 = px[3];
                float h0v[16];
                { float4 v = hx0; h0v[0]=v.x; h0v[1]=v.y; h0v[2]=v.z; h0v[3]=v.w; }
                { float4 v = hx1; h0v[4]=v.x; h0v[5]=v.y; h0v[6]=v.z; h0v[7]=v.w; }
                { float4 v = hx2; h0v[8]=v.x; h0v[9]=v.y; h0v[10]=v.z; h0v[11]=v.w; }
                { float4 v = hx3; h0v[12]=v.x; h0v[13]=v.y; h0v[14]=v.z; h0v[15]=v.w; }
                float t[16]; float sum = 0.f;
#pragma unroll
                for (int i = 0; i < 16; i++) {
                    t[i] = h0v[i] + bf2f((uint32)SH(s)[l * 136 + ds + i]);
                    sum += t[i];
                }
                sum += __shfl_xor(sum, 1); sum += __shfl_xor(sum, 2); sum += __shfl_xor(sum, 4);
                float mean = sum * (1.f / 128.f);
                float vs = 0.f;
#pragma unroll
                for (int i = 0; i < 16; i++) { float d = t[i] - mean; vs += d * d; }
                vs += __shfl_xor(vs, 1); vs += __shfl_xor(vs, 2); vs += __shfl_xor(vs, 4);
                float rs = rsqrtf(vs * (1.f / 128.f) + 1e-5f);
                float h1v[16];
#pragma unroll
                for (int i = 0; i < 16; i++)
                    h1v[i] = (t[i] - mean) * rs * g[i] + be[i];
                store16bf(SH(s) + l * 136 + ds, h1v);  // own addrs
            }
        }
    }
    __syncthreads();                                   // B8: h1 visible (both s)

    // ================= FFN (two K=256 rounds; FFN2 shares weights) ===========
    f32x4 fa[2][4];   // [s][{00,01,10,11}]
#pragma unroll
    for (int s = 0; s < 2; s++)
#pragma unroll
        for (int q = 0; q < 4; q++) fa[s][q] = f32x4{0.f,0.f,0.f,0.f};
    const int col0 = wave * 32 + lh, col1 = col0 + 16;
#pragma unroll
    for (int r = 0; r < 2; r++) {
        // ---- FFN1 per s: 4 column-tiles per wave -> s_m(s) ----
#pragma unroll
        for (int s = 0; s < 2; s++) {
            bf16x8 ah[2][4];
#pragma unroll
            for (int mt = 0; mt < 2; mt++)
#pragma unroll
                for (int kk = 0; kk < 4; kk++)
                    ah[mt][kk] = *(const bf16x8*)(SH(s) + (mt * 16 + lh) * 136 + kk * 32 + lg * 8);
            float b1v[4];
#pragma unroll
            for (int j = 0; j < 4; j++) b1v[j] = b1[(r * 16 + wave * 4 + j) * 16 + lh];
#pragma unroll
            for (int j = 0; j < 4; j++) {
                bf16x8 bw[4];
                {
                    const int nt = (r * 16 + wave * 4 + j) * 16 + lh;
#pragma unroll
                    for (int kk = 0; kk < 4; kk++)
                        bw[kk] = *(const bf16x8*)(w1_bf + (size_t)nt * 128 + kk * 32 + lg * 8);
                }
                f32x4 a0 = {0.f,0.f,0.f,0.f}, a1 = {0.f,0.f,0.f,0.f};
                PRIO_HI();
#pragma unroll
                for (int kk = 0; kk < 4; kk++) {
                    a0 = MFMA(ah[0][kk], bw[kk], a0);
                    a1 = MFMA(ah[1][kk], bw[kk], a1);
                }
                PRIO_LO();
                const float bias = b1v[j];
                const int cl = (wave * 4 + j) * 16 + lh;
                const int r0 = lg * 4;
#pragma unroll
                for (int i = 0; i < 4; i++) {
                    SM(s)[(r0 + i) * 260 + cl]      = f2bf_hw(fmaxf(a0[i] + bias, 0.f));
                    SM(s)[(16 + r0 + i) * 260 + cl] = f2bf_hw(fmaxf(a1[i] + bias, 0.f));
                }
            }
        }
        __syncthreads();                               // B9(r): f1 visible (both s)
        // ---- FFN2: shared w2 slices, 2 chains per load ----
#pragma unroll
        for (int kk = 0; kk < 8; kk++) {
            bf16x8 wp0 = *(const bf16x8*)(w2_bf + (size_t)col0 * 512 + r * 256 + kk * 32 + lg * 8);
            bf16x8 wp1 = *(const bf16x8*)(w2_bf + (size_t)col1 * 512 + r * 256 + kk * 32 + lg * 8);
            PRIO_HI();
#pragma unroll
            for (int s = 0; s < 2; s++) {
                bf16x8 a0 = *(const bf16x8*)(SM(s) + lh * 260 + kk * 32 + lg * 8);
                bf16x8 a1 = *(const bf16x8*)(SM(s) + (16 + lh) * 260 + kk * 32 + lg * 8);
                fa[s][0] = MFMA(a0, wp0, fa[s][0]);
                fa[s][1] = MFMA(a1, wp0, fa[s][1]);
                fa[s][2] = MFMA(a0, wp1, fa[s][2]);
                fa[s][3] = MFMA(a1, wp1, fa[s][3]);
            }
            PRIO_LO();
        }
        __syncthreads();                               // B10(r): f1 reads done
    }
    // ---- f2 -> s_mf(s) (fp32, stride 130) ----
    {
        const float bi0 = b2[col0], bi1 = b2[col1];
#pragma unroll
        for (int s = 0; s < 2; s++) {
#pragma unroll
            for (int i = 0; i < 4; i++) {
                SMF(s)[(lg * 4 + i) * 130 + col0]      = fa[s][0][i] + bi0;
                SMF(s)[(16 + lg * 4 + i) * 130 + col0] = fa[s][1][i] + bi0;
                SMF(s)[(lg * 4 + i) * 130 + col1]      = fa[s][2][i] + bi1;
                SMF(s)[(16 + lg * 4 + i) * 130 + col1] = fa[s][3][i] + bi1;
            }
        }
    }
    __syncthreads();                                   // B11: f2 visible

    // ================= LN2 + out + h2 -> s_h(s), per s =======================
    {
        float g[16], be[16];
        {
            const float4* pg = (const float4*)(ln2g + ds);
            const float4* pb = (const float4*)(ln2b + ds);
#pragma unroll
            for (int q = 0; q < 4; q++) {
                float4 vg = pg[q], vb = pb[q];
                g[4*q]=vg.x; g[4*q+1]=vg.y; g[4*q+2]=vg.z; g[4*q+3]=vg.w;
                be[4*q]=vb.x; be[4*q+1]=vb.y; be[4*q+2]=vb.z; be[4*q+3]=vb.w;
            }
        }
#pragma unroll
        for (int s = 0; s < 2; s++) {
            float t[16]; float sum = 0.f;
#pragma unroll
            for (int i = 0; i < 16; i++) {
                t[i] = bf2f((uint32)SH(s)[l * 136 + ds + i]) + SMF(s)[l * 130 + ds + i];
                sum += t[i];
            }
            sum += __shfl_xor(sum, 1); sum += __shfl_xor(sum, 2); sum += __shfl_xor(sum, 4);
            float mean = sum * (1.f / 128.f);
            float vs = 0.f;
#pragma unroll
            for (int i = 0; i < 16; i++) { float d = t[i] - mean; vs += d * d; }
            vs += __shfl_xor(vs, 1); vs += __shfl_xor(vs, 2); vs += __shfl_xor(vs, 4);
            float rs = rsqrtf(vs * (1.f / 128.f) + 1e-5f);
            float h2v[16];
#pragma unroll
            for (int i = 0; i < 16; i++)
                h2v[i] = (t[i] - mean) * rs * g[i] + be[i];
            float4* po = (float4*)(out_xt + (size_t)(n0 + s) * 4096 + tid * 16);
#pragma unroll
            for (int q = 0; q < 4; q++)
                po[q] = make_float4(h2v[4 * q], h2v[4 * q + 1], h2v[4 * q + 2], h2v[4 * q + 3]);
            store16bf(SH(s) + l * 136 + ds, h2v);      // own addrs
        }
    }
    __syncthreads();                                   // B12: h2 visible

    // ================= GCN weight GEMM (shared weights) ======================
    {
        bf16x8 wb[2][4];
#pragma unroll
        for (int j = 0; j < 2; j++)
#pragma unroll
            for (int kk = 0; kk < 4; kk++)
                wb[j][kk] = *(const bf16x8*)(wg_bf + (size_t)((wave * 2 + j) * 16 + lh) * 128 + kk * 32 + lg * 8);
#pragma unroll
        for (int s = 0; s < 2; s++) {
            bf16x8 ag[2][4];
#pragma unroll
            for (int mt = 0; mt < 2; mt++)
#pragma unroll
                for (int kk = 0; kk < 4; kk++)
                    ag[mt][kk] = *(const bf16x8*)(SH(s) + (mt * 16 + lh) * 136 + kk * 32 + lg * 8);
            ushort_t* hp = hh + (size_t)(n0 + s) * 4096;
#pragma unroll
            for (int j = 0; j < 2; j++) {
                f32x4 a0 = {0.f,0.f,0.f,0.f}, a1 = {0.f,0.f,0.f,0.f};
                PRIO_HI();
#pragma unroll
                for (int kk = 0; kk < 4; kk++) {
                    a0 = MFMA(ag[0][kk], wb[j][kk], a0);
                    a1 = MFMA(ag[1][kk], wb[j][kk], a1);
                }
                PRIO_LO();
                const int col = (wave * 2 + j) * 16 + lh;
                const int r0 = lg * 4;
#pragma unroll
                for (int i = 0; i < 4; i++) {
                    hp[(r0 + i) * 128 + col]      = f2bf_hw(a0[i]);
                    hp[(16 + r0 + i) * 128 + col] = f2bf_hw(a1[i]);
                }
            }
        }
    }
#undef SH
#undef SVT
#undef SM
#undef SMF
}

// ---------------------------------------------------------------------------
// GCN support kernels
// ---------------------------------------------------------------------------
__global__ __launch_bounds__(1024)
void k_scan(const int* __restrict__ count, int* offs, int* cursor) {
    __shared__ int s[KDIM];
    int b = blockIdx.x, i = threadIdx.x;
    int c = count[b * KDIM + i];
    s[i] = c; __syncthreads();
#pragma unroll 1
    for (int off = 1; off < KDIM; off <<= 1) {
        int t = (i >= off) ? s[i - off] : 0;
        __syncthreads();
        s[i] += t;
        __syncthreads();
    }
    int excl = s[i] - c;
    offs[b * KDIM + i] = excl;
    cursor[b * KDIM + i] = excl;
}

__global__ void k_fill(const int* __restrict__ ei, int* cursor, int* elist) {
    int idx = blockIdx.x * 256 + threadIdx.x;
    if (idx >= BDIM * EDIM) return;
    int b = idx / EDIM, e = idx - b * EDIM;
    int col = ei[(size_t)b * 2 * EDIM + EDIM + e];
    int pos = atomicAdd(&cursor[b * KDIM + col], 1);
    elist[(size_t)b * EDIM + pos] = e;
}

// One block per node (XCD-swizzled: each XCD gets a contiguous 512-node range
// of a single batch -> per-XCD L2 working set 8 MB instead of 33 MB).
// DUAL-CHAIN edge loop: 2 rows in flight, next pair's indices prefetched.
__global__ __launch_bounds__(256)
void k_gather(const int* __restrict__ ei, const float* __restrict__ ew,
              const float* __restrict__ deg, const int* __restrict__ offs,
              const int* __restrict__ count, const int* __restrict__ elist,
              const ushort_t* __restrict__ hh, const float* __restrict__ gcn_b,
              float* __restrict__ out)
{
    const int bid  = blockIdx.x;
    const int node = (bid & 7) * (NSEQ / 8) + (bid >> 3);   // bijective XCD swizzle
    const int b = node >> 10, i = node & 1023;
    const int tid = threadIdx.x;
    const float dcol = rsqrtf(deg[node]);
    const int off = offs[node], cnt = count[node];
    const ushort_t* hhb = hh + ((size_t)b * KDIM) * 4096;
    const int* elb = elist + (size_t)b * EDIM;
    const int* eib = ei + (size_t)b * 2 * EDIM;
    const float* ewb = ew + (size_t)b * EDIM;
    const float* degb = deg + b * KDIM;

    float acc[16];
    {
        const uint4* ph = (const uint4*)(hhb + (size_t)i * 4096 + tid * 16);
        uint4 a = ph[0], bb = ph[1];
        float tmp[16]; unpack8(a, tmp); unpack8(bb, tmp + 8);
        float nrm = dcol * dcol;
#pragma unroll
        for (int k = 0; k < 16; k++) acc[k] = tmp[k] * nrm;
    }
    if (cnt > 0) {
        int rowA, rowB = 0; float wA, wB = 0.f;
        {
            int eA = elb[off];
            rowA = eib[eA]; wA = ewb[eA];
            if (cnt > 1) { int eB = elb[off + 1]; rowB = eib[eB]; wB = ewb[eB]; }
        }
        for (int t = 0; t < cnt; t += 2) {
            const bool hasB = (t + 1 < cnt);
            const uint4* pA = (const uint4*)(hhb + (size_t)rowA * 4096 + tid * 16);
            uint4 a0 = pA[0], a1 = pA[1];
            uint4 b0 = make_uint4(0, 0, 0, 0), b1 = make_uint4(0, 0, 0, 0);
            if (hasB) {
                const uint4* pB = (const uint4*)(hhb + (size_t)rowB * 4096 + tid * 16);
                b0 = pB[0]; b1 = pB[1];
            }
            float nA = rsqrtf(degb[rowA]) * wA * dcol;
            float nB = hasB ? rsqrtf(degb[rowB]) * wB * dcol : 0.f;
            int rA2 = 0, rB2 = 0; float wA2 = 0.f, wB2 = 0.f;
            if (t + 2 < cnt) { int e = elb[off + t + 2]; rA2 = eib[e]; wA2 = ewb[e]; }
            if (t + 3 < cnt) { int e = elb[off + t + 3]; rB2 = eib[e]; wB2 = ewb[e]; }
            float tA[16]; unpack8(a0, tA); unpack8(a1, tA + 8);
#pragma unroll
            for (int k = 0; k < 16; k++) acc[k] += tA[k] * nA;
            float tB[16]; unpack8(b0, tB); unpack8(b1, tB + 8);
#pragma unroll
            for (int k = 0; k < 16; k++) acc[k] += tB[k] * nB;
            rowA = rA2; wA = wA2; rowB = rB2; wB = wB2;
        }
    }
    const int d0 = (tid * 16) & 127;
    float4* po = (float4*)(out + (size_t)node * 4096 + tid * 16);
#pragma unroll
    for (int q = 0; q < 4; q++) {
        float4 xo = po[q];
        xo.x += acc[4 * q]     + gcn_b[d0 + 4 * q];
        xo.y += acc[4 * q + 1] + gcn_b[d0 + 4 * q + 1];
        xo.z += acc[4 * q + 2] + gcn_b[d0 + 4 * q + 2];
        xo.w += acc[4 * q + 3] + gcn_b[d0 + 4 * q + 3];
        po[q] = xo;
    }
}

// ---------------------------------------------------------------------------
extern "C" void kernel_launch(void* const* d_in, const int* in_sizes, int n_in,
                              void* d_out, int out_size, void* d_ws, size_t ws_size,
                              hipStream_t stream) {
    const float* x     = (const float*)d_in[0];
    const int*   ei    = (const int*)d_in[1];
    const float* ew    = (const float*)d_in[2];
    const float* w_qkv = (const float*)d_in[3];
    const float* b_qkv = (const float*)d_in[4];
    const float* w_out = (const float*)d_in[5];
    const float* b_out = (const float*)d_in[6];
    const float* w1    = (const float*)d_in[7];
    const float* b1    = (const float*)d_in[8];
    const float* w2    = (const float*)d_in[9];
    const float* b2    = (const float*)d_in[10];
    const float* ln1g  = (const float*)d_in[11];
    const float* ln1b  = (const float*)d_in[12];
    const float* ln2g  = (const float*)d_in[13];
    const float* ln2b  = (const float*)d_in[14];
    const float* gcnw  = (const float*)d_in[15];
    const float* gcnb  = (const float*)d_in[16];
    float* out = (float*)d_out;

    // ws layout (bytes): weights 425984 | deg/count/offs/cursor 4x16384 | elist 262144 | hh 33554432
    char* ws = (char*)d_ws;
    ushort_t* wbf   = (ushort_t*)ws;
    ushort_t* wq_bf = wbf;
    ushort_t* wo_bf = wbf + 49152;
    ushort_t* w1_bf = wbf + 65536;
    ushort_t* w2_bf = wbf + 131072;
    ushort_t* wg_bf = wbf + 196608;
    float*    deg   = (float*)(ws + 425984);
    int*      count = (int*)(ws + 442368);
    int*      offs  = (int*)(ws + 458752);
    int*      cursor= (int*)(ws + 475136);
    int*      elist = (int*)(ws + 491520);
    ushort_t* hh    = (ushort_t*)(ws + 753664);

    k_prep<<<(NWCVT + 255) / 256, 256, 0, stream>>>(w_qkv, w_out, w1, w2, gcnw, wbf, deg, count);
    k_transformer<<<NSEQ / 2, 256, 0, stream>>>(x, wq_bf, b_qkv, wo_bf, b_out,
                                                w1_bf, b1, w2_bf, b2, wg_bf,
                                                ln1g, ln1b, ln2g, ln2b,
                                                ei, ew, deg, count, out, hh);
    k_scan<<<BDIM, 1024, 0, stream>>>(count, offs, cursor);
    k_fill<<<256, 256, 0, stream>>>(ei, cursor, elist);
    k_gather<<<NSEQ, 256, 0, stream>>>(ei, ew, deg, offs, count, elist, hh, gcnb, out);
}

// Round 23
// 271.905 us; speedup vs baseline: 1.1421x; 1.0047x over previous
//
#include <hip/hip_runtime.h>
#include <hip/hip_bf16.h>

// Problem constants
#define BDIM 4
#define KDIM 1024
#define EDIM 16384
#define NSEQ (BDIM * KDIM)   // 4096
#define REG  25856           // per-sequence LDS region stride (bytes)
#define MOFF 9216            // s_m offset within region (after s_vt [128][36])

typedef unsigned short ushort_t;
typedef unsigned int   uint32;

typedef __bf16 bf16x8 __attribute__((ext_vector_type(8)));
typedef float  f32x4  __attribute__((ext_vector_type(4)));

#define MFMA(A, B, C) __builtin_amdgcn_mfma_f32_16x16x32_bf16((A), (B), (C), 0, 0, 0)
#define PRIO_HI() __builtin_amdgcn_s_setprio(1)
#define PRIO_LO() __builtin_amdgcn_s_setprio(0)

__device__ __forceinline__ float bf2f(uint32 u) {
    union { uint32 i; float f; } v; v.i = u << 16; return v.f;
}
__device__ __forceinline__ ushort_t f2bf(float f) {
    union { float f; uint32 i; } v; v.f = f;
    uint32 r = (v.i + 0x7fffu + ((v.i >> 16) & 1u)) >> 16;
    return (ushort_t)r;
}
// hardware packed cvt: {lo=bf16(a), hi=bf16(b)}, RNE
__device__ __forceinline__ uint32 cvtpk(float a, float b) {
    uint32 r;
    asm("v_cvt_pk_bf16_f32 %0, %1, %2" : "=v"(r) : "v"(a), "v"(b));
    return r;
}
__device__ __forceinline__ ushort_t f2bf_hw(float f) { return (ushort_t)cvtpk(f, f); }

__device__ __forceinline__ void unpack8(uint4 v, float* dst) {
    const uint32* pv = (const uint32*)&v;
#pragma unroll
    for (int q = 0; q < 4; q++) {
        uint32 w = pv[q];
        dst[2 * q]     = bf2f(w & 0xffffu);
        dst[2 * q + 1] = bf2f(w >> 16);
    }
}
// pack 16 floats -> 16 bf16 (32B) at p (16B-aligned)
__device__ __forceinline__ void store16bf(ushort_t* p, const float* v) {
    uint32 w[8];
#pragma unroll
    for (int q = 0; q < 8; q++) w[q] = cvtpk(v[2 * q], v[2 * q + 1]);
    ((uint4*)p)[0] = make_uint4(w[0], w[1], w[2], w[3]);
    ((uint4*)p)[1] = make_uint4(w[4], w[5], w[6], w[7]);
}

// ---------------------------------------------------------------------------
// Weight pre-conversion fp32 -> bf16 into ws (+ fused deg/count init):
//   wqkv [384][128] @0 | wout [128][128] @49152 | w1 [512][128] @65536
//   w2 [128][512] @131072 | gcnw [128][128] @196608   (elements)
// ---------------------------------------------------------------------------
#define NWCVT 212992
__global__ void k_prep(const float* __restrict__ wq, const float* __restrict__ wo,
                       const float* __restrict__ w1, const float* __restrict__ w2,
                       const float* __restrict__ wg, ushort_t* __restrict__ dst,
                       float* __restrict__ deg, int* __restrict__ count) {
    int i = blockIdx.x * 256 + threadIdx.x;
    if (i >= NWCVT) return;
    if (i < BDIM * KDIM) { deg[i] = 1.0f; count[i] = 0; }   // fused k_init
    float v;
    if      (i <  49152) v = wq[i];
    else if (i <  65536) v = wo[i - 49152];
    else if (i < 131072) v = w1[i - 65536];
    else if (i < 196608) v = w2[i - 131072];
    else                 v = wg[i - 196608];
    dst[i] = f2bf(v);
}

// ---------------------------------------------------------------------------
// Fused transformer layer (session optimum): 2 seq/block, shared-weight
// QKV/W_out/FFN2/GCN, barrier-free striped attention, 12 barriers/block,
// T5 s_setprio around MFMA clusters (VGPR 84 -> 3 blocks/CU), PLUS fused
// degcount: 32 edge-atomics per block issued at kernel start, draining
// under the 200+ us of MFMA work.
// NO launch_bounds min-waves (pinned miscompile r7/r8).
// LDS 2 x 25856 = 51712 B.
// Region: s_h[32][136]<alias>s_vt[128][36] @0; s_m[32][260]|s_mf[32][130] @9216.
// ---------------------------------------------------------------------------
__global__ __launch_bounds__(256)
void k_transformer(const float* __restrict__ x,
                   const ushort_t* __restrict__ wq_bf, const float* __restrict__ b_qkv,
                   const ushort_t* __restrict__ wo_bf, const float* __restrict__ b_out,
                   const ushort_t* __restrict__ w1_bf, const float* __restrict__ b1,
                   const ushort_t* __restrict__ w2_bf, const float* __restrict__ b2,
                   const ushort_t* __restrict__ wg_bf,
                   const float* __restrict__ ln1g, const float* __restrict__ ln1b,
                   const float* __restrict__ ln2g, const float* __restrict__ ln2b,
                   const int* __restrict__ ei, const float* __restrict__ ew,
                   float* __restrict__ deg, int* __restrict__ count,
                   float* __restrict__ out_xt, ushort_t* __restrict__ hh)
{
    const int n0   = blockIdx.x * 2;
    const int tid  = threadIdx.x;
    const int wave = tid >> 6;
    const int lane = tid & 63;
    const int lh   = lane & 15;      // M-row / N-col within 16x16 tile
    const int lg   = lane >> 4;      // k-group (8 elems each)
    const int l    = tid >> 3;       // per-thread row (LN phases)
    const int ds   = (tid & 7) * 16;

    // ---- fused degcount: 32 edges/block, atomics drain under MFMA work ----
    if (tid < 32) {
        const int idx = blockIdx.x * 32 + tid;      // 2048*32 = 65536 = B*E
        const int eb  = idx >> 14;                  // / EDIM
        const int e   = idx & (EDIM - 1);
        const int col = ei[(size_t)eb * 2 * EDIM + EDIM + e];
        atomicAdd(&deg[eb * KDIM + col], ew[(size_t)eb * EDIM + e]);
        atomicAdd(&count[eb * KDIM + col], 1);
    }

    __shared__ __align__(16) char smem[2 * REG];
#define SH(s)  ((ushort_t*)(smem + (s) * REG))
#define SVT(s) ((ushort_t*)(smem + (s) * REG))
#define SM(s)  ((ushort_t*)(smem + (s) * REG + MOFF))
#define SMF(s) ((float*)(smem + (s) * REG + MOFF))

    // ---- load h0 for both sequences -> s_h(s) (bf16) ----
#pragma unroll
    for (int s = 0; s < 2; s++) {
        const float4* px = (const float4*)(x + (size_t)(n0 + s) * 4096 + tid * 16);
        float h0[16];
#pragma unroll
        for (int q = 0; q < 4; q++) {
            float4 v = px[q];
            h0[4 * q] = v.x; h0[4 * q + 1] = v.y; h0[4 * q + 2] = v.z; h0[4 * q + 3] = v.w;
        }
        store16bf(SH(s) + l * 136 + ds, h0);
    }
    __syncthreads();                                   // B1

    // ================= QKV (shared weights, 2 chains per load) ===============
    {
        bf16x8 af[2][2][4];   // [s][mt][kk]
#pragma unroll
        for (int s = 0; s < 2; s++)
#pragma unroll
            for (int mt = 0; mt < 2; mt++)
#pragma unroll
                for (int kk = 0; kk < 4; kk++)
                    af[s][mt][kk] = *(const bf16x8*)(SH(s) + (mt * 16 + lh) * 136 + kk * 32 + lg * 8);
        __syncthreads();                               // B2: s_h dead; V^T may write region0

        const int ntb = wave * 6;
        float biasv[6];
#pragma unroll
        for (int j = 0; j < 6; j++) biasv[j] = b_qkv[(ntb + j) * 16 + lh];
#pragma unroll
        for (int j = 0; j < 6; j++) {
            bf16x8 bw[4];
#pragma unroll
            for (int kk = 0; kk < 4; kk++)
                bw[kk] = *(const bf16x8*)(wq_bf + (size_t)((ntb + j) * 16 + lh) * 128 + kk * 32 + lg * 8);
            f32x4 A[2][2];
#pragma unroll
            for (int s = 0; s < 2; s++) { A[s][0] = f32x4{0.f,0.f,0.f,0.f}; A[s][1] = f32x4{0.f,0.f,0.f,0.f}; }
            PRIO_HI();
#pragma unroll
            for (int kk = 0; kk < 4; kk++) {
#pragma unroll
                for (int s = 0; s < 2; s++) {
                    A[s][0] = MFMA(af[s][0][kk], bw[kk], A[s][0]);
                    A[s][1] = MFMA(af[s][1][kk], bw[kk], A[s][1]);
                }
            }
            PRIO_LO();
            const int nt  = ntb + j;
            const int col = nt * 16 + lh;
            const float bias = biasv[j];
#pragma unroll
            for (int s = 0; s < 2; s++) {
                if (nt < 16) {          // Q (cols 0-127) | K (cols 128-255)
                    const int r0 = lg * 4;
#pragma unroll
                    for (int i = 0; i < 4; i++) {
                        SM(s)[(r0 + i) * 260 + col]      = f2bf_hw(A[s][0][i] + bias);
                        SM(s)[(16 + r0 + i) * 260 + col] = f2bf_hw(A[s][1][i] + bias);
                    }
                } else {                // V -> transposed s_vt[dh][key] (region0)
                    const int vc = col - 256;
                    uint32 p01 = cvtpk(A[s][0][0] + bias, A[s][0][1] + bias);
                    uint32 p23 = cvtpk(A[s][0][2] + bias, A[s][0][3] + bias);
                    uint32 q01 = cvtpk(A[s][1][0] + bias, A[s][1][1] + bias);
                    uint32 q23 = cvtpk(A[s][1][2] + bias, A[s][1][3] + bias);
                    *(uint32*)&SVT(s)[vc * 36 + lg * 4]          = p01;
                    *(uint32*)&SVT(s)[vc * 36 + lg * 4 + 2]      = p23;
                    *(uint32*)&SVT(s)[vc * 36 + 16 + lg * 4]     = q01;
                    *(uint32*)&SVT(s)[vc * 36 + 16 + lg * 4 + 2] = q23;
                }
            }
        }
    }
    __syncthreads();                                   // B3: Q,K,V^T visible (both s)

    // ============ attention: BARRIER-FREE per-wave striped section ===========
    {
        // W_out weights + biases loaded ONCE, early (consumed after B6)
        bf16x8 wbo[2][4];
#pragma unroll
        for (int j = 0; j < 2; j++)
#pragma unroll
            for (int kk = 0; kk < 4; kk++)
                wbo[j][kk] = *(const bf16x8*)(wo_bf + (size_t)((wave * 2 + j) * 16 + lh) * 128 + kk * 32 + lg * 8);
        float bo0 = b_out[(wave * 2 + 0) * 16 + lh];
        float bo1 = b_out[(wave * 2 + 1) * 16 + lh];

#pragma unroll
        for (int s = 0; s < 2; s++) {
            // ---- QK^T both heads (must precede P: P(hd0) overwrites Q(hd1)) --
            f32x4 sA[2][2][2];   // [hd][mt][nt]
            bf16x8 bz = {};
            PRIO_HI();
#pragma unroll
            for (int hd = 0; hd < 2; hd++) {
                const int h8 = wave * 2 + hd;
#pragma unroll
                for (int mt = 0; mt < 2; mt++) {
                    bf16x8 aq = *(const bf16x8*)(SM(s) + (mt * 16 + lh) * 260 + h8 * 16 + (lg & 1) * 8);
#pragma unroll
                    for (int nt = 0; nt < 2; nt++) {
                        bf16x8 bk = bz;
                        if (lg < 2)
                            bk = *(const bf16x8*)(SM(s) + (nt * 16 + lh) * 260 + 128 + h8 * 16 + lg * 8);
                        f32x4 z = {0.f,0.f,0.f,0.f};
                        sA[hd][mt][nt] = MFMA(aq, bk, z);
                    }
                }
            }
            PRIO_LO();
            // ---- softmax + P into own stripes (wave-local) ----
#pragma unroll
            for (int hd = 0; hd < 2; hd++) {
                const int cb = hd ? (128 + wave * 32) : (wave * 32);
#pragma unroll
                for (int mt = 0; mt < 2; mt++) {
#pragma unroll
                    for (int i = 0; i < 4; i++) {
                        float e0 = __expf(sA[hd][mt][0][i] * 0.25f);
                        float e1 = __expf(sA[hd][mt][1][i] * 0.25f);
                        float sm = e0 + e1;
                        sm += __shfl_xor(sm, 1); sm += __shfl_xor(sm, 2);
                        sm += __shfl_xor(sm, 4); sm += __shfl_xor(sm, 8);
                        float inv = 1.0f / sm;
                        const int row = mt * 16 + lg * 4 + i;
                        SM(s)[row * 260 + cb + lh]      = f2bf_hw(e0 * inv);
                        SM(s)[row * 260 + cb + 16 + lh] = f2bf_hw(e1 * inv);
                    }
                }
            }
            // ---- PV -> O into own col stripe (wave-local) ----
            PRIO_HI();
#pragma unroll
            for (int hd = 0; hd < 2; hd++) {
                const int h8 = wave * 2 + hd;
                const int cb = hd ? (128 + wave * 32) : (wave * 32);
                bf16x8 bv = *(const bf16x8*)(SVT(s) + (h8 * 16 + lh) * 36 + lg * 8);
#pragma unroll
                for (int mt = 0; mt < 2; mt++) {
                    bf16x8 ap = *(const bf16x8*)(SM(s) + (mt * 16 + lh) * 260 + cb + lg * 8);
                    f32x4 z = {0.f,0.f,0.f,0.f};
                    f32x4 o = MFMA(ap, bv, z);
                    const int r0 = mt * 16 + lg * 4, c = h8 * 16 + lh;
#pragma unroll
                    for (int i = 0; i < 4; i++)
                        SM(s)[(r0 + i) * 260 + c] = f2bf_hw(o[i]);
                }
            }
            PRIO_LO();
        }
        __syncthreads();                               // B6: O complete (both s)
        // W_out -> u (bf16, region0(s)); shared wbo, 2 chains
#pragma unroll
        for (int s = 0; s < 2; s++) {
            bf16x8 af2[2][4];
#pragma unroll
            for (int mt = 0; mt < 2; mt++)
#pragma unroll
                for (int kk = 0; kk < 4; kk++)
                    af2[mt][kk] = *(const bf16x8*)(SM(s) + (mt * 16 + lh) * 260 + kk * 32 + lg * 8);
#pragma unroll
            for (int j = 0; j < 2; j++) {
                f32x4 a0 = {0.f,0.f,0.f,0.f}, a1 = {0.f,0.f,0.f,0.f};
                PRIO_HI();
#pragma unroll
                for (int kk = 0; kk < 4; kk++) {
                    a0 = MFMA(af2[0][kk], wbo[j][kk], a0);
                    a1 = MFMA(af2[1][kk], wbo[j][kk], a1);
                }
                PRIO_LO();
                const int col = (wave * 2 + j) * 16 + lh;
                const float bias = j ? bo1 : bo0;
#pragma unroll
                for (int i = 0; i < 4; i++) {
                    SH(s)[(lg * 4 + i) * 136 + col]      = f2bf_hw(a0[i] + bias);
                    SH(s)[(16 + lg * 4 + i) * 136 + col] = f2bf_hw(a1[i] + bias);
                }
            }
        }
        __syncthreads();                               // B7: u visible (both s)
        // LN1: h1 = LN(h0 + u) -> s_h(s), both s (gamma/beta loaded once)
        {
            float g[16], be[16];
            {
                const float4* pg = (const float4*)(ln1g + ds);
                const float4* pb = (const float4*)(ln1b + ds);
#pragma unroll
                for (int q = 0; q < 4; q++) {
                    float4 vg = pg[q], vb = pb[q];
                    g[4*q]=vg.x; g[4*q+1]=vg.y; g[4*q+2]=vg.z; g[4*q+3]=vg.w;
                    be[4*q]=vb.x; be[4*q+1]=vb.y; be[4*q+2]=vb.z; be[4*q+3]=vb.w;
                }
            }
#pragma unroll
            for (int s = 0; s < 2; s++) {
                const float4* px = (const float4*)(x + (size_t)(n0 + s) * 4096 + tid * 16);
                float4 hx0 = px[0], hx1 = px[1], hx2 = px[2], hx3 = px[3];
                float h0v[16];
                { float4 v = hx0; h0v[0]=v.x; h0v[1]=v.y; h0v[2]=v.z; h0v[3]=v.w; }
                { float4 v = hx1; h0v[4]=v.x; h0v[5]=v.y; h0v[6]=v.z; h0v[7]=v.w; }
                { float4 v = hx2; h0v[8]=v.x; h0v[9]=v.y; h0v[10]=v.z; h0v[11]=v.w; }
                { float4 v = hx3; h0v[12]=v.x; h0v[13]=v.y; h0v[14]=v.z; h0v[15]=v.w; }
                float t[16]; float sum = 0.f;
#pragma unroll
                for (int i = 0; i < 16; i++) {
                    t[i] = h0v[i] + bf2f((uint32)SH(s)[l * 136 + ds + i]);
                    sum += t[i];
                }
                sum += __shfl_xor(sum, 1); sum += __shfl_xor(sum, 2); sum += __shfl_xor(sum, 4);
                float mean = sum * (1.f / 128.f);
                float vs = 0.f;
#pragma unroll
                for (int i = 0; i < 16; i++) { float d = t[i] - mean; vs += d * d; }
                vs += __shfl_xor(vs, 1); vs += __shfl_xor(vs, 2); vs += __shfl_xor(vs, 4);
                float rs = rsqrtf(vs * (1.f / 128.f) + 1e-5f);
                float h1v[16];
#pragma unroll
                for (int i = 0; i < 16; i++)
                    h1v[i] = (t[i] - mean) * rs * g[i] + be[i];
                store16bf(SH(s) + l * 136 + ds, h1v);  // own addrs
            }
        }
    }
    __syncthreads();                                   // B8: h1 visible (both s)

    // ================= FFN (two K=256 rounds; FFN2 shares weights) ===========
    f32x4 fa[2][4];   // [s][{00,01,10,11}]
#pragma unroll
    for (int s = 0; s < 2; s++)
#pragma unroll
        for (int q = 0; q < 4; q++) fa[s][q] = f32x4{0.f,0.f,0.f,0.f};
    const int col0 = wave * 32 + lh, col1 = col0 + 16;
#pragma unroll
    for (int r = 0; r < 2; r++) {
        // ---- FFN1 per s: 4 column-tiles per wave -> s_m(s) ----
#pragma unroll
        for (int s = 0; s < 2; s++) {
            bf16x8 ah[2][4];
#pragma unroll
            for (int mt = 0; mt < 2; mt++)
#pragma unroll
                for (int kk = 0; kk < 4; kk++)
                    ah[mt][kk] = *(const bf16x8*)(SH(s) + (mt * 16 + lh) * 136 + kk * 32 + lg * 8);
            float b1v[4];
#pragma unroll
            for (int j = 0; j < 4; j++) b1v[j] = b1[(r * 16 + wave * 4 + j) * 16 + lh];
#pragma unroll
            for (int j = 0; j < 4; j++) {
                bf16x8 bw[4];
                {
                    const int nt = (r * 16 + wave * 4 + j) * 16 + lh;
#pragma unroll
                    for (int kk = 0; kk < 4; kk++)
                        bw[kk] = *(const bf16x8*)(w1_bf + (size_t)nt * 128 + kk * 32 + lg * 8);
                }
                f32x4 a0 = {0.f,0.f,0.f,0.f}, a1 = {0.f,0.f,0.f,0.f};
                PRIO_HI();
#pragma unroll
                for (int kk = 0; kk < 4; kk++) {
                    a0 = MFMA(ah[0][kk], bw[kk], a0);
                    a1 = MFMA(ah[1][kk], bw[kk], a1);
                }
                PRIO_LO();
                const float bias = b1v[j];
                const int cl = (wave * 4 + j) * 16 + lh;
                const int r0 = lg * 4;
#pragma unroll
                for (int i = 0; i < 4; i++) {
                    SM(s)[(r0 + i) * 260 + cl]      = f2bf_hw(fmaxf(a0[i] + bias, 0.f));
                    SM(s)[(16 + r0 + i) * 260 + cl] = f2bf_hw(fmaxf(a1[i] + bias, 0.f));
                }
            }
        }
        __syncthreads();                               // B9(r): f1 visible (both s)
        // ---- FFN2: shared w2 slices, 2 chains per load ----
#pragma unroll
        for (int kk = 0; kk < 8; kk++) {
            bf16x8 wp0 = *(const bf16x8*)(w2_bf + (size_t)col0 * 512 + r * 256 + kk * 32 + lg * 8);
            bf16x8 wp1 = *(const bf16x8*)(w2_bf + (size_t)col1 * 512 + r * 256 + kk * 32 + lg * 8);
            PRIO_HI();
#pragma unroll
            for (int s = 0; s < 2; s++) {
                bf16x8 a0 = *(const bf16x8*)(SM(s) + lh * 260 + kk * 32 + lg * 8);
                bf16x8 a1 = *(const bf16x8*)(SM(s) + (16 + lh) * 260 + kk * 32 + lg * 8);
                fa[s][0] = MFMA(a0, wp0, fa[s][0]);
                fa[s][1] = MFMA(a1, wp0, fa[s][1]);
                fa[s][2] = MFMA(a0, wp1, fa[s][2]);
                fa[s][3] = MFMA(a1, wp1, fa[s][3]);
            }
            PRIO_LO();
        }
        __syncthreads();                               // B10(r): f1 reads done
    }
    // ---- f2 -> s_mf(s) (fp32, stride 130) ----
    {
        const float bi0 = b2[col0], bi1 = b2[col1];
#pragma unroll
        for (int s = 0; s < 2; s++) {
#pragma unroll
            for (int i = 0; i < 4; i++) {
                SMF(s)[(lg * 4 + i) * 130 + col0]      = fa[s][0][i] + bi0;
                SMF(s)[(16 + lg * 4 + i) * 130 + col0] = fa[s][1][i] + bi0;
                SMF(s)[(lg * 4 + i) * 130 + col1]      = fa[s][2][i] + bi1;
                SMF(s)[(16 + lg * 4 + i) * 130 + col1] = fa[s][3][i] + bi1;
            }
        }
    }
    __syncthreads();                                   // B11: f2 visible

    // ================= LN2 + out + h2 -> s_h(s), per s =======================
    {
        float g[16], be[16];
        {
            const float4* pg = (const float4*)(ln2g + ds);
            const float4* pb = (const float4*)(ln2b + ds);
#pragma unroll
            for (int q = 0; q < 4; q++) {
                float4 vg = pg[q], vb = pb[q];
                g[4*q]=vg.x; g[4*q+1]=vg.y; g[4*q+2]=vg.z; g[4*q+3]=vg.w;
                be[4*q]=vb.x; be[4*q+1]=vb.y; be[4*q+2]=vb.z; be[4*q+3]=vb.w;
            }
        }
#pragma unroll
        for (int s = 0; s < 2; s++) {
            float t[16]; float sum = 0.f;
#pragma unroll
            for (int i = 0; i < 16; i++) {
                t[i] = bf2f((uint32)SH(s)[l * 136 + ds + i]) + SMF(s)[l * 130 + ds + i];
                sum += t[i];
            }
            sum += __shfl_xor(sum, 1); sum += __shfl_xor(sum, 2); sum += __shfl_xor(sum, 4);
            float mean = sum * (1.f / 128.f);
            float vs = 0.f;
#pragma unroll
            for (int i = 0; i < 16; i++) { float d = t[i] - mean; vs += d * d; }
            vs += __shfl_xor(vs, 1); vs += __shfl_xor(vs, 2); vs += __shfl_xor(vs, 4);
            float rs = rsqrtf(vs * (1.f / 128.f) + 1e-5f);
            float h2v[16];
#pragma unroll
            for (int i = 0; i < 16; i++)
                h2v[i] = (t[i] - mean) * rs * g[i] + be[i];
            float4* po = (float4*)(out_xt + (size_t)(n0 + s) * 4096 + tid * 16);
#pragma unroll
            for (int q = 0; q < 4; q++)
                po[q] = make_float4(h2v[4 * q], h2v[4 * q + 1], h2v[4 * q + 2], h2v[4 * q + 3]);
            store16bf(SH(s) + l * 136 + ds, h2v);      // own addrs
        }
    }
    __syncthreads();                                   // B12: h2 visible

    // ================= GCN weight GEMM (shared weights) ======================
    {
        bf16x8 wb[2][4];
#pragma unroll
        for (int j = 0; j < 2; j++)
#pragma unroll
            for (int kk = 0; kk < 4; kk++)
                wb[j][kk] = *(const bf16x8*)(wg_bf + (size_t)((wave * 2 + j) * 16 + lh) * 128 + kk * 32 + lg * 8);
#pragma unroll
        for (int s = 0; s < 2; s++) {
            bf16x8 ag[2][4];
#pragma unroll
            for (int mt = 0; mt < 2; mt++)
#pragma unroll
                for (int kk = 0; kk < 4; kk++)
                    ag[mt][kk] = *(const bf16x8*)(SH(s) + (mt * 16 + lh) * 136 + kk * 32 + lg * 8);
            ushort_t* hp = hh + (size_t)(n0 + s) * 4096;
#pragma unroll
            for (int j = 0; j < 2; j++) {
                f32x4 a0 = {0.f,0.f,0.f,0.f}, a1 = {0.f,0.f,0.f,0.f};
                PRIO_HI();
#pragma unroll
                for (int kk = 0; kk < 4; kk++) {
                    a0 = MFMA(ag[0][kk], wb[j][kk], a0);
                    a1 = MFMA(ag[1][kk], wb[j][kk], a1);
                }
                PRIO_LO();
                const int col = (wave * 2 + j) * 16 + lh;
                const int r0 = lg * 4;
#pragma unroll
                for (int i = 0; i < 4; i++) {
                    hp[(r0 + i) * 128 + col]      = f2bf_hw(a0[i]);
                    hp[(16 + r0 + i) * 128 + col] = f2bf_hw(a1[i]);
                }
            }
        }
    }
#undef SH
#undef SVT
#undef SM
#undef SMF
}

// ---------------------------------------------------------------------------
// GCN support kernels
// ---------------------------------------------------------------------------
// Hierarchical shuffle scan: per-wave inclusive scan (shfl_up, 64 lanes) ->
// 16-lane scan of wave sums -> add base. 2 barriers (was 20).
__global__ __launch_bounds__(1024)
void k_scan(const int* __restrict__ count, int* offs, int* cursor) {
    __shared__ int wsum[16];
    const int b = blockIdx.x, i = threadIdx.x;
    const int lane = i & 63;
    const int c = count[b * KDIM + i];
    int v = c;
#pragma unroll
    for (int d = 1; d < 64; d <<= 1) {
        int t = __shfl_up(v, d);
        if (lane >= d) v += t;
    }
    if (lane == 63) wsum[i >> 6] = v;
    __syncthreads();
    if (i < 16) {
        int w = wsum[i];
#pragma unroll
        for (int d = 1; d < 16; d <<= 1) {
            int t = __shfl_up(w, d);
            if (i >= d) w += t;
        }
        wsum[i] = w;
    }
    __syncthreads();
    const int base = (i >= 64) ? wsum[(i >> 6) - 1] : 0;
    const int excl = v + base - c;
    offs[b * KDIM + i]   = excl;
    cursor[b * KDIM + i] = excl;
}

__global__ void k_fill(const int* __restrict__ ei, int* cursor, int* elist) {
    int idx = blockIdx.x * 256 + threadIdx.x;
    if (idx >= BDIM * EDIM) return;
    int b = idx / EDIM, e = idx - b * EDIM;
    int col = ei[(size_t)b * 2 * EDIM + EDIM + e];
    int pos = atomicAdd(&cursor[b * KDIM + col], 1);
    elist[(size_t)b * EDIM + pos] = e;
}

// One block per node (XCD-swizzled: each XCD gets a contiguous 512-node range
// of a single batch -> per-XCD L2 working set 8 MB instead of 33 MB).
// DUAL-CHAIN edge loop: 2 rows in flight, next pair's indices prefetched.
__global__ __launch_bounds__(256)
void k_gather(const int* __restrict__ ei, const float* __restrict__ ew,
              const float* __restrict__ deg, const int* __restrict__ offs,
              const int* __restrict__ count, const int* __restrict__ elist,
              const ushort_t* __restrict__ hh, const float* __restrict__ gcn_b,
              float* __restrict__ out)
{
    const int bid  = blockIdx.x;
    const int node = (bid & 7) * (NSEQ / 8) + (bid >> 3);   // bijective XCD swizzle
    const int b = node >> 10, i = node & 1023;
    const int tid = threadIdx.x;
    const float dcol = rsqrtf(deg[node]);
    const int off = offs[node], cnt = count[node];
    const ushort_t* hhb = hh + ((size_t)b * KDIM) * 4096;
    const int* elb = elist + (size_t)b * EDIM;
    const int* eib = ei + (size_t)b * 2 * EDIM;
    const float* ewb = ew + (size_t)b * EDIM;
    const float* degb = deg + b * KDIM;

    float acc[16];
    {
        const uint4* ph = (const uint4*)(hhb + (size_t)i * 4096 + tid * 16);
        uint4 a = ph[0], bb = ph[1];
        float tmp[16]; unpack8(a, tmp); unpack8(bb, tmp + 8);
        float nrm = dcol * dcol;
#pragma unroll
        for (int k = 0; k < 16; k++) acc[k] = tmp[k] * nrm;
    }
    if (cnt > 0) {
        int rowA, rowB = 0; float wA, wB = 0.f;
        {
            int eA = elb[off];
            rowA = eib[eA]; wA = ewb[eA];
            if (cnt > 1) { int eB = elb[off + 1]; rowB = eib[eB]; wB = ewb[eB]; }
        }
        for (int t = 0; t < cnt; t += 2) {
            const bool hasB = (t + 1 < cnt);
            const uint4* pA = (const uint4*)(hhb + (size_t)rowA * 4096 + tid * 16);
            uint4 a0 = pA[0], a1 = pA[1];
            uint4 b0 = make_uint4(0, 0, 0, 0), b1 = make_uint4(0, 0, 0, 0);
            if (hasB) {
                const uint4* pB = (const uint4*)(hhb + (size_t)rowB * 4096 + tid * 16);
                b0 = pB[0]; b1 = pB[1];
            }
            float nA = rsqrtf(degb[rowA]) * wA * dcol;
            float nB = hasB ? rsqrtf(degb[rowB]) * wB * dcol : 0.f;
            int rA2 = 0, rB2 = 0; float wA2 = 0.f, wB2 = 0.f;
            if (t + 2 < cnt) { int e = elb[off + t + 2]; rA2 = eib[e]; wA2 = ewb[e]; }
            if (t + 3 < cnt) { int e = elb[off + t + 3]; rB2 = eib[e]; wB2 = ewb[e]; }
            float tA[16]; unpack8(a0, tA); unpack8(a1, tA + 8);
#pragma unroll
            for (int k = 0; k < 16; k++) acc[k] += tA[k] * nA;
            float tB[16]; unpack8(b0, tB); unpack8(b1, tB + 8);
#pragma unroll
            for (int k = 0; k < 16; k++) acc[k] += tB[k] * nB;
            rowA = rA2; wA = wA2; rowB = rB2; wB = wB2;
        }
    }
    const int d0 = (tid * 16) & 127;
    float4* po = (float4*)(out + (size_t)node * 4096 + tid * 16);
#pragma unroll
    for (int q = 0; q < 4; q++) {
        float4 xo = po[q];
        xo.x += acc[4 * q]     + gcn_b[d0 + 4 * q];
        xo.y += acc[4 * q + 1] + gcn_b[d0 + 4 * q + 1];
        xo.z += acc[4 * q + 2] + gcn_b[d0 + 4 * q + 2];
        xo.w += acc[4 * q + 3] + gcn_b[d0 + 4 * q + 3];
        po[q] = xo;
    }
}

// ---------------------------------------------------------------------------
extern "C" void kernel_launch(void* const* d_in, const int* in_sizes, int n_in,
                              void* d_out, int out_size, void* d_ws, size_t ws_size,
                              hipStream_t stream) {
    const float* x     = (const float*)d_in[0];
    const int*   ei    = (const int*)d_in[1];
    const float* ew    = (const float*)d_in[2];
    const float* w_qkv = (const float*)d_in[3];
    const float* b_qkv = (const float*)d_in[4];
    const float* w_out = (const float*)d_in[5];
    const float* b_out = (const float*)d_in[6];
    const float* w1    = (const float*)d_in[7];
    const float* b1    = (const float*)d_in[8];
    const float* w2    = (const float*)d_in[9];
    const float* b2    = (const float*)d_in[10];
    const float* ln1g  = (const float*)d_in[11];
    const float* ln1b  = (const float*)d_in[12];
    const float* ln2g  = (const float*)d_in[13];
    const float* ln2b  = (const float*)d_in[14];
    const float* gcnw  = (const float*)d_in[15];
    const float* gcnb  = (const float*)d_in[16];
    float* out = (float*)d_out;

    // ws layout (bytes): weights 425984 | deg/count/offs/cursor 4x16384 | elist 262144 | hh 33554432
    char* ws = (char*)d_ws;
    ushort_t* wbf   = (ushort_t*)ws;
    ushort_t* wq_bf = wbf;
    ushort_t* wo_bf = wbf + 49152;
    ushort_t* w1_bf = wbf + 65536;
    ushort_t* w2_bf = wbf + 131072;
    ushort_t* wg_bf = wbf + 196608;
    float*    deg   = (float*)(ws + 425984);
    int*      count = (int*)(ws + 442368);
    int*      offs  = (int*)(ws + 458752);
    int*      cursor= (int*)(ws + 475136);
    int*      elist = (int*)(ws + 491520);
    ushort_t* hh    = (ushort_t*)(ws + 753664);

    k_prep<<<(NWCVT + 255) / 256, 256, 0, stream>>>(w_qkv, w_out, w1, w2, gcnw, wbf, deg, count);
    k_transformer<<<NSEQ / 2, 256, 0, stream>>>(x, wq_bf, b_qkv, wo_bf, b_out,
                                                w1_bf, b1, w2_bf, b2, wg_bf,
                                                ln1g, ln1b, ln2g, ln2b,
                                                ei, ew, deg, count, out, hh);
    k_scan<<<BDIM, 1024, 0, stream>>>(count, offs, cursor);
    k_fill<<<256, 256, 0, stream>>>(ei, cursor, elist);
    k_gather<<<NSEQ, 256, 0, stream>>>(ei, ew, deg, offs, count, elist, hh, gcnb, out);
}